// Round 6
// baseline (258.825 us; speedup 1.0000x reference)
//
#include <hip/hip_runtime.h>
#include <math.h>

#define NN 1024
#define FD 64
#define CH 32          // K*H
#define M1D 9
#define M2D 505
#define QH 253         // q in [0,252] stored
#define THALF 2273     // half-grid points
#define KPAD 4608
#define KSPLIT 16
#define KCHUNK 288     // 4608/16 = 9*32

// ws layout (floats); ws_size = 256 MiB (observed via harness poison fill)
#define OFF_TW    0                       // 1010 (pad 1024)
#define OFF_WP    1024                    // 18 (pad 32)
#define OFF_SUMX  1056                    // 128 (pad to 1184)
#define OFF_G1    1184                    // 9*253*64*2 = 291456
#define OFF_GMAT  292640                  // 4608*64 = 294912
#define OFF_XL    587552                  // 65536
#define OFF_XR    653088                  // 65536
#define OFF_AGG   718624                  // 2048*512 = 1048576
#define OFF_PART  1767200                 // 16*131072 = 2097152
#define OFF_Y     3864352                 // 2048*4608 = 9437184 ; first 259072 ALIASED as T early
#define OFF_A2    13301536                // 16384*512 = 8388608
#define OFF_WT    21690144                // 64*512 = 32768
// total = 21,722,912 floats = 86.9 MB

__global__ __launch_bounds__(512) void prep_kernel(float* __restrict__ tw,
                                                   float* __restrict__ wp,
                                                   float* __restrict__ sumx) {
    int t = threadIdx.x;
    if (t < M2D) {
        double a = -2.0 * M_PI * (double)t / (double)M2D;
        tw[2*t] = (float)cos(a); tw[2*t+1] = (float)sin(a);
    }
    if (t < M1D) {
        double a = -2.0 * M_PI * (double)t / (double)M1D;
        wp[2*t] = (float)cos(a); wp[2*t+1] = (float)sin(a);
    }
    if (t < 128) sumx[t] = 0.f;
}

// builds both T and Wt (merged to save a launch)
// T[r][m2] (row stride 512): r=2q+reim. T[2q][m2]=cos(-2pi q m2/505), T[2q+1][m2]=-sin(-..)
// Wt[m][col] (row stride 512): col=2q+reim. Wt[m][2q]=cos(-2pi q m/505), [2q+1]=sin(-..)
__global__ __launch_bounds__(256) void build_tw_kernel(const float* __restrict__ tw,
                                                       float* __restrict__ T,
                                                       float* __restrict__ Wt) {
    int idx = blockIdx.x * 256 + threadIdx.x;
    if (idx < 506 * 512) {
        int r = idx >> 9, m2 = idx & 511;
        float v = 0.f;
        if (m2 < M2D) {
            int q = r >> 1;
            int t = (q * m2) % M2D;
            v = (r & 1) ? -tw[2*t+1] : tw[2*t];
        }
        T[idx] = v;
    } else if (idx < 506 * 512 + 64 * 512) {
        int i2 = idx - 506 * 512;
        int m = i2 >> 9, col = i2 & 511;
        float v = 0.f;
        if (col < 506) {
            int q = col >> 1;
            int t = (q * m) % M2D;
            v = (col & 1) ? tw[2*t+1] : tw[2*t];
        }
        Wt[i2] = v;
    }
}

// 32 blocks x 64 threads: partial column sums of x
__global__ __launch_bounds__(64) void sumx_kernel(const float* __restrict__ x,
                                                  float* __restrict__ sumx) {
    int b = blockIdx.x >> 4, chunk = blockIdx.x & 15;
    int f = threadIdx.x;
    const float* xb = x + (size_t)b * NN * FD;
    float acc = 0.f;
    int j0 = chunk * 64;
    #pragma unroll 4
    for (int j = j0; j < j0 + 64; j++) acc += xb[j*FD + f];
    atomicAdd(&sumx[b*FD + f], acc);
}

// 2048 blocks x 64 threads: xl = x@Wl+bl, xr = x@Wr+br
__global__ __launch_bounds__(64) void proj_kernel(const float* __restrict__ x,
                                                  const float* __restrict__ Wl, const float* __restrict__ bl,
                                                  const float* __restrict__ Wr, const float* __restrict__ br,
                                                  float* __restrict__ xl, float* __restrict__ xr) {
    int node = blockIdx.x, tid = threadIdx.x;
    __shared__ float xrow[FD];
    xrow[tid] = x[(size_t)node*FD + tid];
    __syncthreads();
    int c = tid & 31;
    const float* W = (tid < 32) ? Wl : Wr;
    float acc = (tid < 32) ? bl[c] : br[c];
    #pragma unroll
    for (int f = 0; f < FD; f++) acc += xrow[f] * W[f*CH + c];
    float* dst = (tid < 32) ? xl : xr;
    dst[(size_t)node*CH + c] = acc;
}

// G1 rows = T @ Wm[m1] : per m1, [506 x 505(pad512)] @ [505 x 64]
// Register-batched + double-buffered staging.
__global__ __launch_bounds__(256) void g1_gemm_kernel(const float* __restrict__ T,
                                                      const float* __restrict__ Wm,
                                                      float* __restrict__ G1) {
    int mt = blockIdx.x, m1 = blockIdx.y;
    int tid = threadIdx.x;
    __shared__ float Ts[64][33];
    __shared__ float Ws[32][64];
    const float* Wmb = Wm + (size_t)m1 * M2D * FD;
    float acc[4][4] = {{0.f}};
    int tm = (tid >> 4) * 4, tf = (tid & 15) * 4;
    int r0 = mt * 64;
    float ra[8], rb[8];
    #pragma unroll
    for (int i = 0; i < 8; i++) {
        int l = tid + i*256;
        int r = l >> 5, kk = l & 31;
        int rr = r0 + r;
        ra[i] = (rr < 506) ? T[(size_t)rr*512 + kk] : 0.f;
    }
    #pragma unroll
    for (int i = 0; i < 8; i++) {
        int l = tid + i*256;
        int kk = l >> 6, f = l & 63;
        rb[i] = (kk < M2D) ? Wmb[(size_t)kk*FD + f] : 0.f;
    }
    for (int k0 = 0; k0 < 512; k0 += 32) {
        #pragma unroll
        for (int i = 0; i < 8; i++) {
            int l = tid + i*256;
            Ts[l >> 5][l & 31] = ra[i];
        }
        #pragma unroll
        for (int i = 0; i < 8; i++) {
            int l = tid + i*256;
            Ws[l >> 6][l & 63] = rb[i];
        }
        __syncthreads();
        if (k0 + 32 < 512) {
            int kn = k0 + 32;
            #pragma unroll
            for (int i = 0; i < 8; i++) {
                int l = tid + i*256;
                int r = l >> 5, kk = l & 31;
                int rr = r0 + r;
                ra[i] = (rr < 506) ? T[(size_t)rr*512 + kn + kk] : 0.f;
            }
            #pragma unroll
            for (int i = 0; i < 8; i++) {
                int l = tid + i*256;
                int kk = l >> 6, f = l & 63;
                int krow = kn + kk;
                rb[i] = (krow < M2D) ? Wmb[(size_t)krow*FD + f] : 0.f;
            }
        }
        #pragma unroll 8
        for (int k = 0; k < 32; k++) {
            float a0 = Ts[tm][k], a1 = Ts[tm+1][k], a2 = Ts[tm+2][k], a3 = Ts[tm+3][k];
            float4 b = *(const float4*)&Ws[k][tf];
            acc[0][0] += a0*b.x; acc[0][1] += a0*b.y; acc[0][2] += a0*b.z; acc[0][3] += a0*b.w;
            acc[1][0] += a1*b.x; acc[1][1] += a1*b.y; acc[1][2] += a1*b.z; acc[1][3] += a1*b.w;
            acc[2][0] += a2*b.x; acc[2][1] += a2*b.y; acc[2][2] += a2*b.z; acc[2][3] += a2*b.w;
            acc[3][0] += a3*b.x; acc[3][1] += a3*b.y; acc[3][2] += a3*b.z; acc[3][3] += a3*b.w;
        }
        __syncthreads();
    }
    #pragma unroll
    for (int i = 0; i < 4; i++) {
        int r = r0 + tm + i;
        if (r >= 506) continue;
        int q = r >> 1, reim = r & 1;
        size_t base = (size_t)(m1*QH + q) * FD;
        #pragma unroll
        for (int j = 0; j < 4; j++)
            G1[(base + tf + j)*2 + reim] = acc[i][j];
    }
}

// Gmat[2t..2t+1][f] from G1: fold 9-point DFT over m1, Hermitian weight, 1/4545
__global__ __launch_bounds__(64) void gmat_kernel(const float* __restrict__ G1,
                                                  const float* __restrict__ wp,
                                                  float* __restrict__ Gmat) {
    int t = blockIdx.x;            // [0, 2304)
    int f = threadIdx.x;
    if (t >= THALF) {
        Gmat[(size_t)(2*t)*FD + f] = 0.f;
        Gmat[(size_t)(2*t+1)*FD + f] = 0.f;
        return;
    }
    int p, q;
    if (t < QH) { p = 0; q = t; }
    else { int u = t - QH; p = 1 + u / M2D; q = u % M2D; }
    float gr = 0.f, gi = 0.f;
    #pragma unroll
    for (int m1 = 0; m1 < M1D; m1++) {
        float ar, ai;
        if (q < QH) { size_t o = ((size_t)(m1*QH + q)*FD + f)*2; ar = G1[o]; ai = G1[o+1]; }
        else        { size_t o = ((size_t)(m1*QH + (M2D - q))*FD + f)*2; ar = G1[o]; ai = -G1[o+1]; }
        int pm = (p * m1) % M1D;
        float cr = wp[2*pm], ci = -wp[2*pm+1];   // cis(+2 pi p m1 / 9)
        gr += ar*cr - ai*ci;
        gi += ar*ci + ai*cr;
    }
    float cfac = (t == 0) ? 1.0f : 2.0f;
    float scale = cfac / 4545.0f;
    Gmat[(size_t)(2*t)*FD + f]   =  gr * scale;
    Gmat[(size_t)(2*t+1)*FD + f] = -gi * scale;
}

// one block (256 thr) per node: softmax Z over all j, sparse clamped gather
__global__ __launch_bounds__(256) void attn_agg_kernel(const float* __restrict__ x,
                                                       const float* __restrict__ adj,
                                                       const float* __restrict__ xl,
                                                       const float* __restrict__ xr,
                                                       const float* __restrict__ sumx,
                                                       float* __restrict__ agg) {
    int node = blockIdx.x;
    int b = node >> 10;
    int tid = threadIdx.x;
    __shared__ float xr_s[CH], Zinv[CH], Ssum[CH];
    __shared__ float red[8][CH];
    __shared__ int act_list[NN];
    __shared__ int act_n;
    __shared__ float qv[8][CH];

    if (tid < CH) xr_s[tid] = xr[(size_t)node*CH + tid];
    if (tid == 0) act_n = 0;
    __syncthreads();

    int c = tid & 31, jl = tid >> 5;
    const float* xlb = xl + ((size_t)b << 10) * CH;
    float zacc = 0.f;
    #pragma unroll 4
    for (int j = jl; j < NN; j += 8) {
        float s = xlb[j*CH + c] + xr_s[c];
        s = s > 0.f ? s : 0.01f * s;
        zacc += __expf(s);
    }
    red[jl][c] = zacc;
    __syncthreads();
    if (tid < CH) {
        float z = 0.f;
        #pragma unroll
        for (int r = 0; r < 8; r++) z += red[r][tid];
        Zinv[tid] = 1.0f / z;
    }
    const float* adjrow = adj + (size_t)node * NN;
    __syncthreads();
    for (int j = tid; j < NN; j += 256) {
        if (adjrow[j] != 0.f) { int p = atomicAdd(&act_n, 1); act_list[p] = j; }
    }
    __syncthreads();
    int nact = act_n;

    float acc0 = 0.f, acc1 = 0.f, sacc = 0.f;
    int f = tid & 63, n0 = tid >> 6;
    int g = f >> 4;
    int c0 = n0*4 + g, c1 = (n0+4)*4 + g;
    const float* xb = x + ((size_t)b << 10) * FD;

    for (int base = 0; base < nact; base += 8) {
        int cnt = min(8, nact - base);
        if (jl < cnt) {
            int j = act_list[base + jl];
            float s = xlb[j*CH + c] + xr_s[c];
            s = s > 0.f ? s : 0.01f * s;
            float p = __expf(s) * Zinv[c];
            float qq = fmaxf(p, 1e-6f) - 1e-6f;
            qv[jl][c] = qq;
            sacc += qq;
        }
        __syncthreads();
        for (int jb = 0; jb < cnt; jb++) {
            int j = act_list[base + jb];
            float xv = xb[j*FD + f];
            acc0 += qv[jb][c0] * xv;
            acc1 += qv[jb][c1] * xv;
        }
        __syncthreads();
    }
    red[jl][c] = sacc;
    __syncthreads();
    if (tid < CH) {
        float s = 0.f;
        #pragma unroll
        for (int r = 0; r < 8; r++) s += red[r][tid];
        Ssum[tid] = s + (float)NN * 1e-6f;
    }
    __syncthreads();
    float sx = sumx[b*FD + f] * 1e-6f;
    agg[(size_t)node*512 + n0*FD + f]       = (acc0 + sx) / Ssum[c0];
    agg[(size_t)node*512 + (n0+4)*FD + f]   = (acc1 + sx) / Ssum[c1];
}

// A2 = agg @ Wt : [16384 x 64] @ [64 x 512]. grid (256 mtiles, 8 ntiles)
// Register-batched staging; A-tile padded to 68 for aligned ds_read_b128.
__global__ __launch_bounds__(256) void a_gemm_kernel(const float* __restrict__ agg,
                                                     const float* __restrict__ Wt,
                                                     float* __restrict__ A2) {
    int mt = blockIdx.x, nt = blockIdx.y;
    int tid = threadIdx.x;
    __shared__ float As2[64][68];   // As2[k][r], pad 68 -> [k][tm] float4-aligned
    __shared__ float Bs[64][64];    // Bs[k][c]
    float acc[4][4] = {{0.f}};
    int tm = (tid >> 4) * 4, tf = (tid & 15) * 4;
    float ra[16], rb[16];
    #pragma unroll
    for (int i = 0; i < 16; i++) {
        int l = tid + i*256;
        int r = l >> 6, k = l & 63;
        ra[i] = agg[(size_t)(mt*64 + r)*64 + k];
    }
    #pragma unroll
    for (int i = 0; i < 16; i++) {
        int l = tid + i*256;
        int k = l >> 6, cc = l & 63;
        rb[i] = Wt[(size_t)k*512 + nt*64 + cc];
    }
    #pragma unroll
    for (int i = 0; i < 16; i++) {
        int l = tid + i*256;
        As2[l & 63][l >> 6] = ra[i];
    }
    #pragma unroll
    for (int i = 0; i < 16; i++) {
        int l = tid + i*256;
        Bs[l >> 6][l & 63] = rb[i];
    }
    __syncthreads();
    #pragma unroll 8
    for (int k = 0; k < 64; k++) {
        float4 a = *(const float4*)&As2[k][tm];
        float4 b = *(const float4*)&Bs[k][tf];
        acc[0][0] += a.x*b.x; acc[0][1] += a.x*b.y; acc[0][2] += a.x*b.z; acc[0][3] += a.x*b.w;
        acc[1][0] += a.y*b.x; acc[1][1] += a.y*b.y; acc[1][2] += a.y*b.z; acc[1][3] += a.y*b.w;
        acc[2][0] += a.z*b.x; acc[2][1] += a.z*b.y; acc[2][2] += a.z*b.z; acc[2][3] += a.z*b.w;
        acc[3][0] += a.w*b.x; acc[3][1] += a.w*b.y; acc[3][2] += a.w*b.z; acc[3][3] += a.w*b.w;
    }
    #pragma unroll
    for (int i = 0; i < 4; i++) {
        float4 v = make_float4(acc[i][0], acc[i][1], acc[i][2], acc[i][3]);
        *(float4*)&A2[(size_t)(mt*64 + tm + i)*512 + nt*64 + tf] = v;
    }
}

// one block (256 thr) per node: Y half-grid from A2 via complex products.
// (p,q) enumerated directly -- no int div/mod, p-twiddles are inline literals.
__global__ __launch_bounds__(256) void y_kernel(const float* __restrict__ A2,
                                                float* __restrict__ Y) {
    int node = blockIdx.x;
    int tid = threadIdx.x;
    __shared__ float2 AL[8][QH];

    const float2* A2c = (const float2*)(A2 + (size_t)(node*8)*512);
    float2 rl[8];
    #pragma unroll
    for (int i = 0; i < 8; i++) {
        int idx = tid + i*256;
        rl[i] = (idx < 8*QH) ? A2c[(idx/QH)*256 + (idx%QH)] : make_float2(0.f, 0.f);
    }
    #pragma unroll
    for (int i = 0; i < 8; i++) {
        int idx = tid + i*256;
        if (idx < 8*QH) AL[idx/QH][idx%QH] = rl[i];
    }
    __syncthreads();

    float* Yrow = Y + (size_t)node * KPAD;
    // zero the pad region: floats [2*THALF, KPAD)
    if (tid < KPAD - 2*THALF) Yrow[2*THALF + tid] = 0.f;

    // cis(-2 pi p / 9), p = 0..4 (fp32-rounded from double)
    const float CPt[5] = {1.0f, 0.766044443119f, 0.173648177667f, -0.5f, -0.939692620786f};
    const float SPt[5] = {0.0f, -0.642787609687f, -0.984807753012f, -0.866025403784f, -0.342020143326f};

    #define Y_BODY(P, Q, QQ, CSIGN)                                            \
    {                                                                          \
        float cp = CPt[P], sp = SPt[P];                                        \
        float Pr = 1.f, Pi = 0.f, rp = 1.f;                                    \
        _Pragma("unroll")                                                      \
        for (int n = 0; n < 8; n++) {                                          \
            float2 Av = AL[n][QQ];                                             \
            float Ar = Av.x, Ai = (CSIGN) * Av.y;                              \
            float Xr = cp - Ar, Xi = sp - Ai;                                  \
            float m2 = Xr*Xr + Xi*Xi;                                          \
            rp *= (sqrtf(m2) + 1e-6f);                                         \
            float nPr = Pr*Xr - Pi*Xi;                                         \
            Pi = Pr*Xi + Pi*Xr; Pr = nPr;                                      \
        }                                                                      \
        float pAbs = sqrtf(Pr*Pr + Pi*Pi);                                     \
        float rp8 = sqrtf(sqrtf(sqrtf(rp)));                                   \
        float s = rp8 / fmaxf(pAbs, 1e-20f);                                   \
        int t = (P == 0) ? (Q) : (QH + ((P)-1)*M2D + (Q));                     \
        *(float2*)&Yrow[2*t] = make_float2(s*Pr, s*Pi);                        \
    }

    // p = 0: q = tid in [0,253)
    if (tid < QH) Y_BODY(0, tid, tid, 1.f);
    // p = 1..4: q = tid (qq/csign via select) and q = tid+256 (always mirrored)
    #pragma unroll
    for (int p = 1; p <= 4; p++) {
        {
            int q = tid;
            int qq = (q < QH) ? q : (M2D - q);
            float cs = (q < QH) ? 1.f : -1.f;
            Y_BODY(p, q, qq, cs);
        }
        {
            int q = tid + 256;
            if (q < M2D) {
                int qq = M2D - q;      // q >= 256 > 253 always
                Y_BODY(p, q, qq, -1.f);
            }
        }
    }
    #undef Y_BODY
}

// partials[kc] = Y[:, kc-chunk] @ Gmat[kc-chunk, :] ; grid (32 Mtiles, 16 kc)
// Register-batched + double-buffered staging; A-tile padded 68 for float4 reads.
__global__ __launch_bounds__(256) void gemm_kernel(const float* __restrict__ Y,
                                                   const float* __restrict__ Gmat,
                                                   float* __restrict__ part) {
    int mtile = blockIdx.x, kc = blockIdx.y;
    int tid = threadIdx.x;
    __shared__ float Yt2[32][68];   // Yt2[k][r], pad 68 -> [k][tm] float4-aligned
    __shared__ float Gt[32][64];
    int m0 = mtile * 64;
    int k0 = kc * KCHUNK;
    float acc[4][4] = {{0.f}};
    int tm = (tid >> 4) * 4;
    int tf = (tid & 15) * 4;
    float ra[8], rb[8];
    #pragma unroll
    for (int i = 0; i < 8; i++) {
        int l = tid + i*256;
        int r = l >> 5, kk = l & 31;
        ra[i] = Y[(size_t)(m0 + r)*KPAD + k0 + kk];
    }
    #pragma unroll
    for (int i = 0; i < 8; i++) {
        int l = tid + i*256;
        int kk = l >> 6, cc = l & 63;
        rb[i] = Gmat[(size_t)(k0 + kk)*FD + cc];
    }
    for (int ks = 0; ks < KCHUNK; ks += 32) {
        #pragma unroll
        for (int i = 0; i < 8; i++) {
            int l = tid + i*256;
            Yt2[l & 31][l >> 5] = ra[i];
        }
        #pragma unroll
        for (int i = 0; i < 8; i++) {
            int l = tid + i*256;
            Gt[l >> 6][l & 63] = rb[i];
        }
        __syncthreads();
        if (ks + 32 < KCHUNK) {
            int kn = k0 + ks + 32;
            #pragma unroll
            for (int i = 0; i < 8; i++) {
                int l = tid + i*256;
                int r = l >> 5, kk = l & 31;
                ra[i] = Y[(size_t)(m0 + r)*KPAD + kn + kk];
            }
            #pragma unroll
            for (int i = 0; i < 8; i++) {
                int l = tid + i*256;
                int kk = l >> 6, cc = l & 63;
                rb[i] = Gmat[(size_t)(kn + kk)*FD + cc];
            }
        }
        #pragma unroll 8
        for (int k = 0; k < 32; k++) {
            float4 a = *(const float4*)&Yt2[k][tm];
            float4 b = *(const float4*)&Gt[k][tf];
            acc[0][0] += a.x*b.x; acc[0][1] += a.x*b.y; acc[0][2] += a.x*b.z; acc[0][3] += a.x*b.w;
            acc[1][0] += a.y*b.x; acc[1][1] += a.y*b.y; acc[1][2] += a.y*b.z; acc[1][3] += a.y*b.w;
            acc[2][0] += a.z*b.x; acc[2][1] += a.z*b.y; acc[2][2] += a.z*b.z; acc[2][3] += a.z*b.w;
            acc[3][0] += a.w*b.x; acc[3][1] += a.w*b.y; acc[3][2] += a.w*b.z; acc[3][3] += a.w*b.w;
        }
        __syncthreads();
    }
    float* prow = part + (size_t)kc * (2048*FD);
    #pragma unroll
    for (int i = 0; i < 4; i++) {
        float4 v = make_float4(acc[i][0], acc[i][1], acc[i][2], acc[i][3]);
        *(float4*)&prow[(size_t)(m0 + tm + i)*FD + tf] = v;
    }
}

// sum 16 partials + bias + mask -> out
__global__ __launch_bounds__(256) void reduce_kernel(const float* __restrict__ part,
                                                     const float* __restrict__ bm,
                                                     const float* __restrict__ mask,
                                                     float* __restrict__ out) {
    int idx = blockIdx.x * 256 + threadIdx.x;   // float4 index over 2048*64/4 = 32768
    if (idx >= 32768) return;
    const float4* p4 = (const float4*)part;
    float4 s = p4[idx];
    #pragma unroll
    for (int kc = 1; kc < KSPLIT; kc++) {
        float4 v = p4[(size_t)kc*32768 + idx];
        s.x += v.x; s.y += v.y; s.z += v.z; s.w += v.w;
    }
    int f0 = (idx & 15) * 4;
    int node = idx >> 4;
    float mk = mask[node];
    s.x = (s.x + bm[f0])   * mk;
    s.y = (s.y + bm[f0+1]) * mk;
    s.z = (s.z + bm[f0+2]) * mk;
    s.w = (s.w + bm[f0+3]) * mk;
    ((float4*)out)[idx] = s;
}

extern "C" void kernel_launch(void* const* d_in, const int* in_sizes, int n_in,
                              void* d_out, int out_size, void* d_ws, size_t ws_size,
                              hipStream_t stream) {
    const float* x    = (const float*)d_in[0];
    const float* adj  = (const float*)d_in[1];
    const float* mask = (const float*)d_in[2];
    const float* Wl   = (const float*)d_in[3];
    const float* bl   = (const float*)d_in[4];
    const float* Wr   = (const float*)d_in[5];
    const float* br   = (const float*)d_in[6];
    const float* Wm   = (const float*)d_in[9];
    const float* bm   = (const float*)d_in[10];
    float* out = (float*)d_out;
    float* ws  = (float*)d_ws;

    float* tw   = ws + OFF_TW;
    float* wp   = ws + OFF_WP;
    float* sumx = ws + OFF_SUMX;
    float* G1   = ws + OFF_G1;
    float* Gmat = ws + OFF_GMAT;
    float* xl   = ws + OFF_XL;
    float* xr   = ws + OFF_XR;
    float* agg  = ws + OFF_AGG;
    float* part = ws + OFF_PART;
    float* T    = ws + OFF_Y;     // alias: T dead before y_kernel writes Y
    float* Y    = ws + OFF_Y;
    float* A2   = ws + OFF_A2;
    float* Wt   = ws + OFF_WT;

    hipLaunchKernelGGL(prep_kernel, dim3(1), dim3(512), 0, stream, tw, wp, sumx);
    hipLaunchKernelGGL(build_tw_kernel, dim3((506*512 + 64*512 + 255)/256), dim3(256), 0, stream, tw, T, Wt);
    hipLaunchKernelGGL(sumx_kernel, dim3(32), dim3(64), 0, stream, x, sumx);
    hipLaunchKernelGGL(proj_kernel, dim3(2048), dim3(64), 0, stream, x, Wl, bl, Wr, br, xl, xr);
    hipLaunchKernelGGL(g1_gemm_kernel, dim3(8, 9), dim3(256), 0, stream, T, Wm, G1);
    hipLaunchKernelGGL(gmat_kernel, dim3(KPAD/2), dim3(64), 0, stream, G1, wp, Gmat);
    hipLaunchKernelGGL(attn_agg_kernel, dim3(2048), dim3(256), 0, stream, x, adj, xl, xr, sumx, agg);
    hipLaunchKernelGGL(a_gemm_kernel, dim3(256, 8), dim3(256), 0, stream, agg, Wt, A2);
    hipLaunchKernelGGL(y_kernel, dim3(2048), dim3(256), 0, stream, A2, Y);
    hipLaunchKernelGGL(gemm_kernel, dim3(32, KSPLIT), dim3(256), 0, stream, Y, Gmat, part);
    hipLaunchKernelGGL(reduce_kernel, dim3(128), dim3(256), 0, stream, part, bm, mask, out);
}

// Round 7
// 240.957 us; speedup vs baseline: 1.0742x; 1.0742x over previous
//
#include <hip/hip_runtime.h>
#include <math.h>

#define NN 1024
#define FD 64
#define CH 32          // K*H
#define M1D 9
#define M2D 505
#define QH 253         // q in [0,252] stored
#define THALF 2273     // half-grid points
#define KPAD 4608
#define KSPLIT 16
#define KCHUNK 288     // 4608/16 = 9*32

#define FSQRT(x) __builtin_amdgcn_sqrtf(x)
#define FRCP(x)  __builtin_amdgcn_rcpf(x)

// ws layout (floats); ws_size = 256 MiB (observed via harness poison fill)
#define OFF_TW    0                       // 1010 (pad 1024)
#define OFF_WP    1024                    // 18 (pad 32)
#define OFF_SUMX  1056                    // 128 (pad to 1184)
#define OFF_G1    1184                    // 9*253*64*2 = 291456
#define OFF_GMAT  292640                  // 4608*64 = 294912
#define OFF_XL    587552                  // 65536
#define OFF_XR    653088                  // 65536
#define OFF_AGG   718624                  // 2048*512 = 1048576
#define OFF_PART  1767200                 // 16*131072 = 2097152
#define OFF_Y     3864352                 // 2048*4608 = 9437184 ; first 259072 ALIASED as T early
#define OFF_A2    13301536                // 16384*512 = 8388608
#define OFF_WT    21690144                // 64*512 = 32768
// total = 21,722,912 floats = 86.9 MB

__global__ __launch_bounds__(512) void prep_kernel(float* __restrict__ tw,
                                                   float* __restrict__ wp,
                                                   float* __restrict__ sumx) {
    int t = threadIdx.x;
    if (t < M2D) {
        double a = -2.0 * M_PI * (double)t / (double)M2D;
        tw[2*t] = (float)cos(a); tw[2*t+1] = (float)sin(a);
    }
    if (t < M1D) {
        double a = -2.0 * M_PI * (double)t / (double)M1D;
        wp[2*t] = (float)cos(a); wp[2*t+1] = (float)sin(a);
    }
    if (t < 128) sumx[t] = 0.f;
}

// builds both T and Wt (merged to save a launch)
__global__ __launch_bounds__(256) void build_tw_kernel(const float* __restrict__ tw,
                                                       float* __restrict__ T,
                                                       float* __restrict__ Wt) {
    int idx = blockIdx.x * 256 + threadIdx.x;
    if (idx < 506 * 512) {
        int r = idx >> 9, m2 = idx & 511;
        float v = 0.f;
        if (m2 < M2D) {
            int q = r >> 1;
            int t = (q * m2) % M2D;
            v = (r & 1) ? -tw[2*t+1] : tw[2*t];
        }
        T[idx] = v;
    } else if (idx < 506 * 512 + 64 * 512) {
        int i2 = idx - 506 * 512;
        int m = i2 >> 9, col = i2 & 511;
        float v = 0.f;
        if (col < 506) {
            int q = col >> 1;
            int t = (q * m) % M2D;
            v = (col & 1) ? tw[2*t+1] : tw[2*t];
        }
        Wt[i2] = v;
    }
}

// 32 blocks x 64 threads: partial column sums of x
__global__ __launch_bounds__(64) void sumx_kernel(const float* __restrict__ x,
                                                  float* __restrict__ sumx) {
    int b = blockIdx.x >> 4, chunk = blockIdx.x & 15;
    int f = threadIdx.x;
    const float* xb = x + (size_t)b * NN * FD;
    float acc = 0.f;
    int j0 = chunk * 64;
    #pragma unroll 4
    for (int j = j0; j < j0 + 64; j++) acc += xb[j*FD + f];
    atomicAdd(&sumx[b*FD + f], acc);
}

// 2048 blocks x 64 threads: xl = x@Wl+bl, xr = x@Wr+br
__global__ __launch_bounds__(64) void proj_kernel(const float* __restrict__ x,
                                                  const float* __restrict__ Wl, const float* __restrict__ bl,
                                                  const float* __restrict__ Wr, const float* __restrict__ br,
                                                  float* __restrict__ xl, float* __restrict__ xr) {
    int node = blockIdx.x, tid = threadIdx.x;
    __shared__ float xrow[FD];
    xrow[tid] = x[(size_t)node*FD + tid];
    __syncthreads();
    int c = tid & 31;
    const float* W = (tid < 32) ? Wl : Wr;
    float acc = (tid < 32) ? bl[c] : br[c];
    #pragma unroll
    for (int f = 0; f < FD; f++) acc += xrow[f] * W[f*CH + c];
    float* dst = (tid < 32) ? xl : xr;
    dst[(size_t)node*CH + c] = acc;
}

// G1 rows = T @ Wm[m1] : per m1, [506 x 505(pad512)] @ [505 x 64]
__global__ __launch_bounds__(256) void g1_gemm_kernel(const float* __restrict__ T,
                                                      const float* __restrict__ Wm,
                                                      float* __restrict__ G1) {
    int mt = blockIdx.x, m1 = blockIdx.y;
    int tid = threadIdx.x;
    __shared__ float Ts[64][33];
    __shared__ float Ws[32][64];
    const float* Wmb = Wm + (size_t)m1 * M2D * FD;
    float acc[4][4] = {{0.f}};
    int tm = (tid >> 4) * 4, tf = (tid & 15) * 4;
    int r0 = mt * 64;
    float ra[8], rb[8];
    #pragma unroll
    for (int i = 0; i < 8; i++) {
        int l = tid + i*256;
        int r = l >> 5, kk = l & 31;
        int rr = r0 + r;
        ra[i] = (rr < 506) ? T[(size_t)rr*512 + kk] : 0.f;
    }
    #pragma unroll
    for (int i = 0; i < 8; i++) {
        int l = tid + i*256;
        int kk = l >> 6, f = l & 63;
        rb[i] = (kk < M2D) ? Wmb[(size_t)kk*FD + f] : 0.f;
    }
    for (int k0 = 0; k0 < 512; k0 += 32) {
        #pragma unroll
        for (int i = 0; i < 8; i++) {
            int l = tid + i*256;
            Ts[l >> 5][l & 31] = ra[i];
        }
        #pragma unroll
        for (int i = 0; i < 8; i++) {
            int l = tid + i*256;
            Ws[l >> 6][l & 63] = rb[i];
        }
        __syncthreads();
        if (k0 + 32 < 512) {
            int kn = k0 + 32;
            #pragma unroll
            for (int i = 0; i < 8; i++) {
                int l = tid + i*256;
                int r = l >> 5, kk = l & 31;
                int rr = r0 + r;
                ra[i] = (rr < 506) ? T[(size_t)rr*512 + kn + kk] : 0.f;
            }
            #pragma unroll
            for (int i = 0; i < 8; i++) {
                int l = tid + i*256;
                int kk = l >> 6, f = l & 63;
                int krow = kn + kk;
                rb[i] = (krow < M2D) ? Wmb[(size_t)krow*FD + f] : 0.f;
            }
        }
        #pragma unroll 8
        for (int k = 0; k < 32; k++) {
            float a0 = Ts[tm][k], a1 = Ts[tm+1][k], a2 = Ts[tm+2][k], a3 = Ts[tm+3][k];
            float4 b = *(const float4*)&Ws[k][tf];
            acc[0][0] += a0*b.x; acc[0][1] += a0*b.y; acc[0][2] += a0*b.z; acc[0][3] += a0*b.w;
            acc[1][0] += a1*b.x; acc[1][1] += a1*b.y; acc[1][2] += a1*b.z; acc[1][3] += a1*b.w;
            acc[2][0] += a2*b.x; acc[2][1] += a2*b.y; acc[2][2] += a2*b.z; acc[2][3] += a2*b.w;
            acc[3][0] += a3*b.x; acc[3][1] += a3*b.y; acc[3][2] += a3*b.z; acc[3][3] += a3*b.w;
        }
        __syncthreads();
    }
    #pragma unroll
    for (int i = 0; i < 4; i++) {
        int r = r0 + tm + i;
        if (r >= 506) continue;
        int q = r >> 1, reim = r & 1;
        size_t base = (size_t)(m1*QH + q) * FD;
        #pragma unroll
        for (int j = 0; j < 4; j++)
            G1[(base + tf + j)*2 + reim] = acc[i][j];
    }
}

// Gmat[2t..2t+1][f] from G1: fold 9-point DFT over m1, Hermitian weight, 1/4545
__global__ __launch_bounds__(64) void gmat_kernel(const float* __restrict__ G1,
                                                  const float* __restrict__ wp,
                                                  float* __restrict__ Gmat) {
    int t = blockIdx.x;            // [0, 2304)
    int f = threadIdx.x;
    if (t >= THALF) {
        Gmat[(size_t)(2*t)*FD + f] = 0.f;
        Gmat[(size_t)(2*t+1)*FD + f] = 0.f;
        return;
    }
    int p, q;
    if (t < QH) { p = 0; q = t; }
    else { int u = t - QH; p = 1 + u / M2D; q = u % M2D; }
    float gr = 0.f, gi = 0.f;
    #pragma unroll
    for (int m1 = 0; m1 < M1D; m1++) {
        float ar, ai;
        if (q < QH) { size_t o = ((size_t)(m1*QH + q)*FD + f)*2; ar = G1[o]; ai = G1[o+1]; }
        else        { size_t o = ((size_t)(m1*QH + (M2D - q))*FD + f)*2; ar = G1[o]; ai = -G1[o+1]; }
        int pm = (p * m1) % M1D;
        float cr = wp[2*pm], ci = -wp[2*pm+1];   // cis(+2 pi p m1 / 9)
        gr += ar*cr - ai*ci;
        gi += ar*ci + ai*cr;
    }
    float scale = (t == 0) ? (1.0f/4545.0f) : (2.0f/4545.0f);
    Gmat[(size_t)(2*t)*FD + f]   =  gr * scale;
    Gmat[(size_t)(2*t+1)*FD + f] = -gi * scale;
}

// one block (256 thr) per node: softmax Z over all j, sparse clamped gather
__global__ __launch_bounds__(256) void attn_agg_kernel(const float* __restrict__ x,
                                                       const float* __restrict__ adj,
                                                       const float* __restrict__ xl,
                                                       const float* __restrict__ xr,
                                                       const float* __restrict__ sumx,
                                                       float* __restrict__ agg) {
    int node = blockIdx.x;
    int b = node >> 10;
    int tid = threadIdx.x;
    __shared__ float xr_s[CH], Zinv[CH], Sinv[CH];
    __shared__ float red[8][CH];
    __shared__ int act_list[NN];
    __shared__ int act_n;
    __shared__ float qv[8][CH];

    if (tid < CH) xr_s[tid] = xr[(size_t)node*CH + tid];
    if (tid == 0) act_n = 0;
    __syncthreads();

    int c = tid & 31, jl = tid >> 5;
    const float* xlb = xl + ((size_t)b << 10) * CH;
    float zacc = 0.f;
    #pragma unroll 4
    for (int j = jl; j < NN; j += 8) {
        float s = xlb[j*CH + c] + xr_s[c];
        s = s > 0.f ? s : 0.01f * s;
        zacc += __expf(s);
    }
    red[jl][c] = zacc;
    __syncthreads();
    if (tid < CH) {
        float z = 0.f;
        #pragma unroll
        for (int r = 0; r < 8; r++) z += red[r][tid];
        Zinv[tid] = 1.0f / z;
    }
    const float* adjrow = adj + (size_t)node * NN;
    __syncthreads();
    for (int j = tid; j < NN; j += 256) {
        if (adjrow[j] != 0.f) { int p = atomicAdd(&act_n, 1); act_list[p] = j; }
    }
    __syncthreads();
    int nact = act_n;

    float acc0 = 0.f, acc1 = 0.f, sacc = 0.f;
    int f = tid & 63, n0 = tid >> 6;
    int g = f >> 4;
    int c0 = n0*4 + g, c1 = (n0+4)*4 + g;
    const float* xb = x + ((size_t)b << 10) * FD;

    for (int base = 0; base < nact; base += 8) {
        int cnt = min(8, nact - base);
        if (jl < cnt) {
            int j = act_list[base + jl];
            float s = xlb[j*CH + c] + xr_s[c];
            s = s > 0.f ? s : 0.01f * s;
            float p = __expf(s) * Zinv[c];
            float qq = fmaxf(p, 1e-6f) - 1e-6f;
            qv[jl][c] = qq;
            sacc += qq;
        }
        __syncthreads();
        for (int jb = 0; jb < cnt; jb++) {
            int j = act_list[base + jb];
            float xv = xb[j*FD + f];
            acc0 += qv[jb][c0] * xv;
            acc1 += qv[jb][c1] * xv;
        }
        __syncthreads();
    }
    red[jl][c] = sacc;
    __syncthreads();
    if (tid < CH) {
        float s = 0.f;
        #pragma unroll
        for (int r = 0; r < 8; r++) s += red[r][tid];
        Sinv[tid] = FRCP(s + (float)NN * 1e-6f);
    }
    __syncthreads();
    float sx = sumx[b*FD + f] * 1e-6f;
    agg[(size_t)node*512 + n0*FD + f]       = (acc0 + sx) * Sinv[c0];
    agg[(size_t)node*512 + (n0+4)*FD + f]   = (acc1 + sx) * Sinv[c1];
}

// A2 = agg @ Wt : [16384 x 64] @ [64 x 512]. grid (256 mtiles, 8 ntiles)
__global__ __launch_bounds__(256) void a_gemm_kernel(const float* __restrict__ agg,
                                                     const float* __restrict__ Wt,
                                                     float* __restrict__ A2) {
    int mt = blockIdx.x, nt = blockIdx.y;
    int tid = threadIdx.x;
    __shared__ float As2[64][68];   // As2[k][r], pad 68 -> [k][tm] float4-aligned
    __shared__ float Bs[64][64];    // Bs[k][c]
    float acc[4][4] = {{0.f}};
    int tm = (tid >> 4) * 4, tf = (tid & 15) * 4;
    float ra[16], rb[16];
    #pragma unroll
    for (int i = 0; i < 16; i++) {
        int l = tid + i*256;
        int r = l >> 6, k = l & 63;
        ra[i] = agg[(size_t)(mt*64 + r)*64 + k];
    }
    #pragma unroll
    for (int i = 0; i < 16; i++) {
        int l = tid + i*256;
        int k = l >> 6, cc = l & 63;
        rb[i] = Wt[(size_t)k*512 + nt*64 + cc];
    }
    #pragma unroll
    for (int i = 0; i < 16; i++) {
        int l = tid + i*256;
        As2[l & 63][l >> 6] = ra[i];
    }
    #pragma unroll
    for (int i = 0; i < 16; i++) {
        int l = tid + i*256;
        Bs[l >> 6][l & 63] = rb[i];
    }
    __syncthreads();
    #pragma unroll 8
    for (int k = 0; k < 64; k++) {
        float4 a = *(const float4*)&As2[k][tm];
        float4 b = *(const float4*)&Bs[k][tf];
        acc[0][0] += a.x*b.x; acc[0][1] += a.x*b.y; acc[0][2] += a.x*b.z; acc[0][3] += a.x*b.w;
        acc[1][0] += a.y*b.x; acc[1][1] += a.y*b.y; acc[1][2] += a.y*b.z; acc[1][3] += a.y*b.w;
        acc[2][0] += a.z*b.x; acc[2][1] += a.z*b.y; acc[2][2] += a.z*b.z; acc[2][3] += a.z*b.w;
        acc[3][0] += a.w*b.x; acc[3][1] += a.w*b.y; acc[3][2] += a.w*b.z; acc[3][3] += a.w*b.w;
    }
    #pragma unroll
    for (int i = 0; i < 4; i++) {
        float4 v = make_float4(acc[i][0], acc[i][1], acc[i][2], acc[i][3]);
        *(float4*)&A2[(size_t)(mt*64 + tm + i)*512 + nt*64 + tf] = v;
    }
}

// one block (256 thr) per node: Y half-grid from A2 via complex products.
// (p,q) enumerated directly; raw v_sqrt/v_rcp (round-6 fix: libm sqrtf/fdiv
// expand to ~9/10-inst correctly-rounded sequences -- 12 sqrt + 1 div per
// element dominated the VALU count).
__global__ __launch_bounds__(256) void y_kernel(const float* __restrict__ A2,
                                                float* __restrict__ Y) {
    int node = blockIdx.x;
    int tid = threadIdx.x;
    __shared__ float2 AL[8][QH];

    const float2* A2c = (const float2*)(A2 + (size_t)(node*8)*512);
    float2 rl[8];
    #pragma unroll
    for (int i = 0; i < 8; i++) {
        int idx = tid + i*256;
        rl[i] = (idx < 8*QH) ? A2c[(idx/QH)*256 + (idx%QH)] : make_float2(0.f, 0.f);
    }
    #pragma unroll
    for (int i = 0; i < 8; i++) {
        int idx = tid + i*256;
        if (idx < 8*QH) AL[idx/QH][idx%QH] = rl[i];
    }
    __syncthreads();

    float* Yrow = Y + (size_t)node * KPAD;
    // zero the pad region: floats [2*THALF, KPAD)
    if (tid < KPAD - 2*THALF) Yrow[2*THALF + tid] = 0.f;

    // cis(-2 pi p / 9), p = 0..4 (fp32-rounded from double)
    const float CPt[5] = {1.0f, 0.766044443119f, 0.173648177667f, -0.5f, -0.939692620786f};
    const float SPt[5] = {0.0f, -0.642787609687f, -0.984807753012f, -0.866025403784f, -0.342020143326f};

    #define Y_BODY(P, Q, QQ, CSIGN)                                            \
    {                                                                          \
        float cp = CPt[P], sp = SPt[P];                                        \
        float Pr = 1.f, Pi = 0.f, rp = 1.f;                                    \
        _Pragma("unroll")                                                      \
        for (int n = 0; n < 8; n++) {                                          \
            float2 Av = AL[n][QQ];                                             \
            float Ar = Av.x, Ai = (CSIGN) * Av.y;                              \
            float Xr = cp - Ar, Xi = sp - Ai;                                  \
            float m2 = Xr*Xr + Xi*Xi;                                          \
            rp *= (FSQRT(m2) + 1e-6f);                                         \
            float nPr = Pr*Xr - Pi*Xi;                                         \
            Pi = Pr*Xi + Pi*Xr; Pr = nPr;                                      \
        }                                                                      \
        float pAbs = FSQRT(Pr*Pr + Pi*Pi);                                     \
        float rp8 = FSQRT(FSQRT(FSQRT(rp)));                                   \
        float s = rp8 * FRCP(fmaxf(pAbs, 1e-20f));                             \
        int t = (P == 0) ? (Q) : (QH + ((P)-1)*M2D + (Q));                     \
        *(float2*)&Yrow[2*t] = make_float2(s*Pr, s*Pi);                        \
    }

    // p = 0: q = tid in [0,253)
    if (tid < QH) Y_BODY(0, tid, tid, 1.f);
    // p = 1..4: q = tid (qq/csign via select) and q = tid+256 (always mirrored)
    #pragma unroll
    for (int p = 1; p <= 4; p++) {
        {
            int q = tid;
            int qq = (q < QH) ? q : (M2D - q);
            float cs = (q < QH) ? 1.f : -1.f;
            Y_BODY(p, q, qq, cs);
        }
        {
            int q = tid + 256;
            if (q < M2D) {
                int qq = M2D - q;      // q >= 256 > 253 always
                Y_BODY(p, q, qq, -1.f);
            }
        }
    }
    #undef Y_BODY
}

// partials[kc] = Y[:, kc-chunk] @ Gmat[kc-chunk, :] ; grid (32 Mtiles, 16 kc)
__global__ __launch_bounds__(256) void gemm_kernel(const float* __restrict__ Y,
                                                   const float* __restrict__ Gmat,
                                                   float* __restrict__ part) {
    int mtile = blockIdx.x, kc = blockIdx.y;
    int tid = threadIdx.x;
    __shared__ float Yt2[32][68];   // Yt2[k][r], pad 68 -> [k][tm] float4-aligned
    __shared__ float Gt[32][64];
    int m0 = mtile * 64;
    int k0 = kc * KCHUNK;
    float acc[4][4] = {{0.f}};
    int tm = (tid >> 4) * 4;
    int tf = (tid & 15) * 4;
    float ra[8], rb[8];
    #pragma unroll
    for (int i = 0; i < 8; i++) {
        int l = tid + i*256;
        int r = l >> 5, kk = l & 31;
        ra[i] = Y[(size_t)(m0 + r)*KPAD + k0 + kk];
    }
    #pragma unroll
    for (int i = 0; i < 8; i++) {
        int l = tid + i*256;
        int kk = l >> 6, cc = l & 63;
        rb[i] = Gmat[(size_t)(k0 + kk)*FD + cc];
    }
    for (int ks = 0; ks < KCHUNK; ks += 32) {
        #pragma unroll
        for (int i = 0; i < 8; i++) {
            int l = tid + i*256;
            Yt2[l & 31][l >> 5] = ra[i];
        }
        #pragma unroll
        for (int i = 0; i < 8; i++) {
            int l = tid + i*256;
            Gt[l >> 6][l & 63] = rb[i];
        }
        __syncthreads();
        if (ks + 32 < KCHUNK) {
            int kn = k0 + ks + 32;
            #pragma unroll
            for (int i = 0; i < 8; i++) {
                int l = tid + i*256;
                int r = l >> 5, kk = l & 31;
                ra[i] = Y[(size_t)(m0 + r)*KPAD + kn + kk];
            }
            #pragma unroll
            for (int i = 0; i < 8; i++) {
                int l = tid + i*256;
                int kk = l >> 6, cc = l & 63;
                rb[i] = Gmat[(size_t)(kn + kk)*FD + cc];
            }
        }
        #pragma unroll 8
        for (int k = 0; k < 32; k++) {
            float4 a = *(const float4*)&Yt2[k][tm];
            float4 b = *(const float4*)&Gt[k][tf];
            acc[0][0] += a.x*b.x; acc[0][1] += a.x*b.y; acc[0][2] += a.x*b.z; acc[0][3] += a.x*b.w;
            acc[1][0] += a.y*b.x; acc[1][1] += a.y*b.y; acc[1][2] += a.y*b.z; acc[1][3] += a.y*b.w;
            acc[2][0] += a.z*b.x; acc[2][1] += a.z*b.y; acc[2][2] += a.z*b.z; acc[2][3] += a.z*b.w;
            acc[3][0] += a.w*b.x; acc[3][1] += a.w*b.y; acc[3][2] += a.w*b.z; acc[3][3] += a.w*b.w;
        }
        __syncthreads();
    }
    float* prow = part + (size_t)kc * (2048*FD);
    #pragma unroll
    for (int i = 0; i < 4; i++) {
        float4 v = make_float4(acc[i][0], acc[i][1], acc[i][2], acc[i][3]);
        *(float4*)&prow[(size_t)(m0 + tm + i)*FD + tf] = v;
    }
}

// sum 16 partials + bias + mask -> out
__global__ __launch_bounds__(256) void reduce_kernel(const float* __restrict__ part,
                                                     const float* __restrict__ bm,
                                                     const float* __restrict__ mask,
                                                     float* __restrict__ out) {
    int idx = blockIdx.x * 256 + threadIdx.x;   // float4 index over 2048*64/4 = 32768
    if (idx >= 32768) return;
    const float4* p4 = (const float4*)part;
    float4 s = p4[idx];
    #pragma unroll
    for (int kc = 1; kc < KSPLIT; kc++) {
        float4 v = p4[(size_t)kc*32768 + idx];
        s.x += v.x; s.y += v.y; s.z += v.z; s.w += v.w;
    }
    int f0 = (idx & 15) * 4;
    int node = idx >> 4;
    float mk = mask[node];
    s.x = (s.x + bm[f0])   * mk;
    s.y = (s.y + bm[f0+1]) * mk;
    s.z = (s.z + bm[f0+2]) * mk;
    s.w = (s.w + bm[f0+3]) * mk;
    ((float4*)out)[idx] = s;
}

extern "C" void kernel_launch(void* const* d_in, const int* in_sizes, int n_in,
                              void* d_out, int out_size, void* d_ws, size_t ws_size,
                              hipStream_t stream) {
    const float* x    = (const float*)d_in[0];
    const float* adj  = (const float*)d_in[1];
    const float* mask = (const float*)d_in[2];
    const float* Wl   = (const float*)d_in[3];
    const float* bl   = (const float*)d_in[4];
    const float* Wr   = (const float*)d_in[5];
    const float* br   = (const float*)d_in[6];
    const float* Wm   = (const float*)d_in[9];
    const float* bm   = (const float*)d_in[10];
    float* out = (float*)d_out;
    float* ws  = (float*)d_ws;

    float* tw   = ws + OFF_TW;
    float* wp   = ws + OFF_WP;
    float* sumx = ws + OFF_SUMX;
    float* G1   = ws + OFF_G1;
    float* Gmat = ws + OFF_GMAT;
    float* xl   = ws + OFF_XL;
    float* xr   = ws + OFF_XR;
    float* agg  = ws + OFF_AGG;
    float* part = ws + OFF_PART;
    float* T    = ws + OFF_Y;     // alias: T dead before y_kernel writes Y
    float* Y    = ws + OFF_Y;
    float* A2   = ws + OFF_A2;
    float* Wt   = ws + OFF_WT;

    hipLaunchKernelGGL(prep_kernel, dim3(1), dim3(512), 0, stream, tw, wp, sumx);
    hipLaunchKernelGGL(build_tw_kernel, dim3((506*512 + 64*512 + 255)/256), dim3(256), 0, stream, tw, T, Wt);
    hipLaunchKernelGGL(sumx_kernel, dim3(32), dim3(64), 0, stream, x, sumx);
    hipLaunchKernelGGL(proj_kernel, dim3(2048), dim3(64), 0, stream, x, Wl, bl, Wr, br, xl, xr);
    hipLaunchKernelGGL(g1_gemm_kernel, dim3(8, 9), dim3(256), 0, stream, T, Wm, G1);
    hipLaunchKernelGGL(gmat_kernel, dim3(KPAD/2), dim3(64), 0, stream, G1, wp, Gmat);
    hipLaunchKernelGGL(attn_agg_kernel, dim3(2048), dim3(256), 0, stream, x, adj, xl, xr, sumx, agg);
    hipLaunchKernelGGL(a_gemm_kernel, dim3(256, 8), dim3(256), 0, stream, agg, Wt, A2);
    hipLaunchKernelGGL(y_kernel, dim3(2048), dim3(256), 0, stream, A2, Y);
    hipLaunchKernelGGL(gemm_kernel, dim3(32, KSPLIT), dim3(256), 0, stream, Y, Gmat, part);
    hipLaunchKernelGGL(reduce_kernel, dim3(128), dim3(256), 0, stream, part, bm, mask, out);
}

// Round 8
// 216.368 us; speedup vs baseline: 1.1962x; 1.1136x over previous
//
#include <hip/hip_runtime.h>
#include <math.h>

#define NN 1024
#define FD 64
#define CH 32          // K*H
#define M1D 9
#define M2D 505
#define QH 253         // q in [0,252] stored
#define THALF 2273     // half-grid points
#define KPAD 4608
#define KSPLIT 16
#define KCHUNK 288     // 4608/16 = 9*32
#define G1SZ 291456    // 9*253*64*2
#define G1KS 8         // K-split factor for g1

#define FSQRT(x) __builtin_amdgcn_sqrtf(x)
#define FRCP(x)  __builtin_amdgcn_rcpf(x)

// ws layout (floats); ws_size = 256 MiB
#define OFF_TW    0                       // 1010 (pad 1024)
#define OFF_WP    1024                    // 18 (pad 32)
#define OFF_SUMX  1056                    // 128 (pad to 1184)
#define OFF_G1    1184                    // 291456
#define OFF_GMAT  292640                  // 4608*64 = 294912
#define OFF_XL    587552                  // 65536
#define OFF_XR    653088                  // 65536
#define OFF_AGG   718624                  // 2048*512 = 1048576
#define OFF_PART  1767200                 // 16*131072 = 2097152
#define OFF_Y     3864352                 // 2048*4608 = 9437184 ; first 259072 ALIASED as T early
#define OFF_A2    13301536                // 16384*512 = 8388608
#define OFF_WT    21690144                // 64*512 = 32768
#define OFF_G1P   21722912                // 8*291456 = 2331648
// total = 24,054,560 floats = 96.2 MB

__global__ __launch_bounds__(512) void prep_kernel(float* __restrict__ tw,
                                                   float* __restrict__ wp,
                                                   float* __restrict__ sumx) {
    int t = threadIdx.x;
    if (t < M2D) {
        double a = -2.0 * M_PI * (double)t / (double)M2D;
        tw[2*t] = (float)cos(a); tw[2*t+1] = (float)sin(a);
    }
    if (t < M1D) {
        double a = -2.0 * M_PI * (double)t / (double)M1D;
        wp[2*t] = (float)cos(a); wp[2*t+1] = (float)sin(a);
    }
    if (t < 128) sumx[t] = 0.f;
}

// builds both T and Wt (merged to save a launch)
__global__ __launch_bounds__(256) void build_tw_kernel(const float* __restrict__ tw,
                                                       float* __restrict__ T,
                                                       float* __restrict__ Wt) {
    int idx = blockIdx.x * 256 + threadIdx.x;
    if (idx < 506 * 512) {
        int r = idx >> 9, m2 = idx & 511;
        float v = 0.f;
        if (m2 < M2D) {
            int q = r >> 1;
            int t = (q * m2) % M2D;
            v = (r & 1) ? -tw[2*t+1] : tw[2*t];
        }
        T[idx] = v;
    } else if (idx < 506 * 512 + 64 * 512) {
        int i2 = idx - 506 * 512;
        int m = i2 >> 9, col = i2 & 511;
        float v = 0.f;
        if (col < 506) {
            int q = col >> 1;
            int t = (q * m) % M2D;
            v = (col & 1) ? tw[2*t+1] : tw[2*t];
        }
        Wt[i2] = v;
    }
}

// 32 blocks x 64 threads: partial column sums of x
__global__ __launch_bounds__(64) void sumx_kernel(const float* __restrict__ x,
                                                  float* __restrict__ sumx) {
    int b = blockIdx.x >> 4, chunk = blockIdx.x & 15;
    int f = threadIdx.x;
    const float* xb = x + (size_t)b * NN * FD;
    float acc = 0.f;
    int j0 = chunk * 64;
    #pragma unroll 4
    for (int j = j0; j < j0 + 64; j++) acc += xb[j*FD + f];
    atomicAdd(&sumx[b*FD + f], acc);
}

// 2048 blocks x 64 threads: xl = x@Wl+bl, xr = x@Wr+br
__global__ __launch_bounds__(64) void proj_kernel(const float* __restrict__ x,
                                                  const float* __restrict__ Wl, const float* __restrict__ bl,
                                                  const float* __restrict__ Wr, const float* __restrict__ br,
                                                  float* __restrict__ xl, float* __restrict__ xr) {
    int node = blockIdx.x, tid = threadIdx.x;
    __shared__ float xrow[FD];
    xrow[tid] = x[(size_t)node*FD + tid];
    __syncthreads();
    int c = tid & 31;
    const float* W = (tid < 32) ? Wl : Wr;
    float acc = (tid < 32) ? bl[c] : br[c];
    #pragma unroll
    for (int f = 0; f < FD; f++) acc += xrow[f] * W[f*CH + c];
    float* dst = (tid < 32) ? xl : xr;
    dst[(size_t)node*CH + c] = acc;
}

// G1 partials: grid (8 mtiles, 9 m1, 8 ksplit), one-shot K=64 tile GEMM per
// block (round-7 fix: the 72-block version left 184 CUs idle — latency-bound
// at 2.8% occupancy).
__global__ __launch_bounds__(256) void g1_gemm_kernel(const float* __restrict__ T,
                                                      const float* __restrict__ Wm,
                                                      float* __restrict__ G1p) {
    int mt = blockIdx.x, m1 = blockIdx.y, ks = blockIdx.z;
    int tid = threadIdx.x;
    __shared__ float As[64][68];    // As[k][r], pad 68 -> [k][tm] float4-aligned
    __shared__ float Bs[64][64];    // Bs[k][f]
    int r0 = mt * 64, k0 = ks * 64;
    const float* Wmb = Wm + (size_t)m1 * M2D * FD;
    float ra[16], rb[16];
    #pragma unroll
    for (int i = 0; i < 16; i++) {
        int l = tid + i*256;
        int r = l >> 6, k = l & 63;
        int rr = r0 + r;
        ra[i] = (rr < 506) ? T[(size_t)rr*512 + k0 + k] : 0.f;   // T zero-padded in k
    }
    #pragma unroll
    for (int i = 0; i < 16; i++) {
        int l = tid + i*256;
        int k = l >> 6, f = l & 63;
        int krow = k0 + k;
        rb[i] = (krow < M2D) ? Wmb[(size_t)krow*FD + f] : 0.f;
    }
    #pragma unroll
    for (int i = 0; i < 16; i++) {
        int l = tid + i*256;
        As[l & 63][l >> 6] = ra[i];
    }
    #pragma unroll
    for (int i = 0; i < 16; i++) {
        int l = tid + i*256;
        Bs[l >> 6][l & 63] = rb[i];
    }
    __syncthreads();
    float acc[4][4] = {{0.f}};
    int tm = (tid >> 4) * 4, tf = (tid & 15) * 4;
    #pragma unroll 8
    for (int k = 0; k < 64; k++) {
        float4 a = *(const float4*)&As[k][tm];
        float4 b = *(const float4*)&Bs[k][tf];
        acc[0][0] += a.x*b.x; acc[0][1] += a.x*b.y; acc[0][2] += a.x*b.z; acc[0][3] += a.x*b.w;
        acc[1][0] += a.y*b.x; acc[1][1] += a.y*b.y; acc[1][2] += a.y*b.z; acc[1][3] += a.y*b.w;
        acc[2][0] += a.z*b.x; acc[2][1] += a.z*b.y; acc[2][2] += a.z*b.z; acc[2][3] += a.z*b.w;
        acc[3][0] += a.w*b.x; acc[3][1] += a.w*b.y; acc[3][2] += a.w*b.z; acc[3][3] += a.w*b.w;
    }
    float* G1k = G1p + (size_t)ks * G1SZ;
    #pragma unroll
    for (int i = 0; i < 4; i++) {
        int r = r0 + tm + i;
        if (r >= 506) continue;
        int q = r >> 1, reim = r & 1;
        size_t base = (size_t)(m1*QH + q) * 128;
        #pragma unroll
        for (int j = 0; j < 4; j++)
            G1k[base + (tf + j)*2 + reim] = acc[i][j];
    }
}

// fold the 8 K-split partials
__global__ __launch_bounds__(256) void g1_reduce_kernel(const float* __restrict__ G1p,
                                                        float* __restrict__ G1) {
    int idx = blockIdx.x * 256 + threadIdx.x;   // float4 over G1SZ/4 = 72864
    if (idx >= G1SZ/4) return;
    const float4* p = (const float4*)G1p;
    float4 s = p[idx];
    #pragma unroll
    for (int ks = 1; ks < G1KS; ks++) {
        float4 v = p[(size_t)ks*(G1SZ/4) + idx];
        s.x += v.x; s.y += v.y; s.z += v.z; s.w += v.w;
    }
    ((float4*)G1)[idx] = s;
}

// Gmat[2t..2t+1][f] from G1: fold 9-point DFT over m1, Hermitian weight, 1/4545
__global__ __launch_bounds__(64) void gmat_kernel(const float* __restrict__ G1,
                                                  const float* __restrict__ wp,
                                                  float* __restrict__ Gmat) {
    int t = blockIdx.x;            // [0, 2304)
    int f = threadIdx.x;
    if (t >= THALF) {
        Gmat[(size_t)(2*t)*FD + f] = 0.f;
        Gmat[(size_t)(2*t+1)*FD + f] = 0.f;
        return;
    }
    int p, q;
    if (t < QH) { p = 0; q = t; }
    else { int u = t - QH; p = 1 + u / M2D; q = u % M2D; }
    float gr = 0.f, gi = 0.f;
    #pragma unroll
    for (int m1 = 0; m1 < M1D; m1++) {
        float ar, ai;
        if (q < QH) { size_t o = ((size_t)(m1*QH + q)*FD + f)*2; ar = G1[o]; ai = G1[o+1]; }
        else        { size_t o = ((size_t)(m1*QH + (M2D - q))*FD + f)*2; ar = G1[o]; ai = -G1[o+1]; }
        int pm = (p * m1) % M1D;
        float cr = wp[2*pm], ci = -wp[2*pm+1];   // cis(+2 pi p m1 / 9)
        gr += ar*cr - ai*ci;
        gi += ar*ci + ai*cr;
    }
    float scale = (t == 0) ? (1.0f/4545.0f) : (2.0f/4545.0f);
    Gmat[(size_t)(2*t)*FD + f]   =  gr * scale;
    Gmat[(size_t)(2*t+1)*FD + f] = -gi * scale;
}

// one block (256 thr) per node: softmax Z over all j, sparse clamped gather
__global__ __launch_bounds__(256) void attn_agg_kernel(const float* __restrict__ x,
                                                       const float* __restrict__ adj,
                                                       const float* __restrict__ xl,
                                                       const float* __restrict__ xr,
                                                       const float* __restrict__ sumx,
                                                       float* __restrict__ agg) {
    int node = blockIdx.x;
    int b = node >> 10;
    int tid = threadIdx.x;
    __shared__ float xr_s[CH], Zinv[CH], Sinv[CH];
    __shared__ float red[8][CH];
    __shared__ int act_list[NN];
    __shared__ int act_n;
    __shared__ float qv[8][CH];

    if (tid < CH) xr_s[tid] = xr[(size_t)node*CH + tid];
    if (tid == 0) act_n = 0;
    __syncthreads();

    int c = tid & 31, jl = tid >> 5;
    const float* xlb = xl + ((size_t)b << 10) * CH;
    float zacc = 0.f;
    #pragma unroll 4
    for (int j = jl; j < NN; j += 8) {
        float s = xlb[j*CH + c] + xr_s[c];
        s = s > 0.f ? s : 0.01f * s;
        zacc += __expf(s);
    }
    red[jl][c] = zacc;
    __syncthreads();
    if (tid < CH) {
        float z = 0.f;
        #pragma unroll
        for (int r = 0; r < 8; r++) z += red[r][tid];
        Zinv[tid] = 1.0f / z;
    }
    const float* adjrow = adj + (size_t)node * NN;
    __syncthreads();
    for (int j = tid; j < NN; j += 256) {
        if (adjrow[j] != 0.f) { int p = atomicAdd(&act_n, 1); act_list[p] = j; }
    }
    __syncthreads();
    int nact = act_n;

    float acc0 = 0.f, acc1 = 0.f, sacc = 0.f;
    int f = tid & 63, n0 = tid >> 6;
    int g = f >> 4;
    int c0 = n0*4 + g, c1 = (n0+4)*4 + g;
    const float* xb = x + ((size_t)b << 10) * FD;

    for (int base = 0; base < nact; base += 8) {
        int cnt = min(8, nact - base);
        if (jl < cnt) {
            int j = act_list[base + jl];
            float s = xlb[j*CH + c] + xr_s[c];
            s = s > 0.f ? s : 0.01f * s;
            float p = __expf(s) * Zinv[c];
            float qq = fmaxf(p, 1e-6f) - 1e-6f;
            qv[jl][c] = qq;
            sacc += qq;
        }
        __syncthreads();
        for (int jb = 0; jb < cnt; jb++) {
            int j = act_list[base + jb];
            float xv = xb[j*FD + f];
            acc0 += qv[jb][c0] * xv;
            acc1 += qv[jb][c1] * xv;
        }
        __syncthreads();
    }
    red[jl][c] = sacc;
    __syncthreads();
    if (tid < CH) {
        float s = 0.f;
        #pragma unroll
        for (int r = 0; r < 8; r++) s += red[r][tid];
        Sinv[tid] = FRCP(s + (float)NN * 1e-6f);
    }
    __syncthreads();
    float sx = sumx[b*FD + f] * 1e-6f;
    agg[(size_t)node*512 + n0*FD + f]       = (acc0 + sx) * Sinv[c0];
    agg[(size_t)node*512 + (n0+4)*FD + f]   = (acc1 + sx) * Sinv[c1];
}

// A2 = agg @ Wt : [16384 x 64] @ [64 x 512]. grid (256 mtiles, 8 ntiles)
__global__ __launch_bounds__(256) void a_gemm_kernel(const float* __restrict__ agg,
                                                     const float* __restrict__ Wt,
                                                     float* __restrict__ A2) {
    int mt = blockIdx.x, nt = blockIdx.y;
    int tid = threadIdx.x;
    __shared__ float As2[64][68];   // As2[k][r], pad 68 -> [k][tm] float4-aligned
    __shared__ float Bs[64][64];    // Bs[k][c]
    float acc[4][4] = {{0.f}};
    int tm = (tid >> 4) * 4, tf = (tid & 15) * 4;
    float ra[16], rb[16];
    #pragma unroll
    for (int i = 0; i < 16; i++) {
        int l = tid + i*256;
        int r = l >> 6, k = l & 63;
        ra[i] = agg[(size_t)(mt*64 + r)*64 + k];
    }
    #pragma unroll
    for (int i = 0; i < 16; i++) {
        int l = tid + i*256;
        int k = l >> 6, cc = l & 63;
        rb[i] = Wt[(size_t)k*512 + nt*64 + cc];
    }
    #pragma unroll
    for (int i = 0; i < 16; i++) {
        int l = tid + i*256;
        As2[l & 63][l >> 6] = ra[i];
    }
    #pragma unroll
    for (int i = 0; i < 16; i++) {
        int l = tid + i*256;
        Bs[l >> 6][l & 63] = rb[i];
    }
    __syncthreads();
    #pragma unroll 8
    for (int k = 0; k < 64; k++) {
        float4 a = *(const float4*)&As2[k][tm];
        float4 b = *(const float4*)&Bs[k][tf];
        acc[0][0] += a.x*b.x; acc[0][1] += a.x*b.y; acc[0][2] += a.x*b.z; acc[0][3] += a.x*b.w;
        acc[1][0] += a.y*b.x; acc[1][1] += a.y*b.y; acc[1][2] += a.y*b.z; acc[1][3] += a.y*b.w;
        acc[2][0] += a.z*b.x; acc[2][1] += a.z*b.y; acc[2][2] += a.z*b.z; acc[2][3] += a.z*b.w;
        acc[3][0] += a.w*b.x; acc[3][1] += a.w*b.y; acc[3][2] += a.w*b.z; acc[3][3] += a.w*b.w;
    }
    #pragma unroll
    for (int i = 0; i < 4; i++) {
        float4 v = make_float4(acc[i][0], acc[i][1], acc[i][2], acc[i][3]);
        *(float4*)&A2[(size_t)(mt*64 + tm + i)*512 + nt*64 + tf] = v;
    }
}

// one block (256 thr) per node: Y half-grid from A2 via complex products.
__global__ __launch_bounds__(256) void y_kernel(const float* __restrict__ A2,
                                                float* __restrict__ Y) {
    int node = blockIdx.x;
    int tid = threadIdx.x;
    __shared__ float2 AL[8][QH];

    const float2* A2c = (const float2*)(A2 + (size_t)(node*8)*512);
    float2 rl[8];
    #pragma unroll
    for (int i = 0; i < 8; i++) {
        int idx = tid + i*256;
        rl[i] = (idx < 8*QH) ? A2c[(idx/QH)*256 + (idx%QH)] : make_float2(0.f, 0.f);
    }
    #pragma unroll
    for (int i = 0; i < 8; i++) {
        int idx = tid + i*256;
        if (idx < 8*QH) AL[idx/QH][idx%QH] = rl[i];
    }
    __syncthreads();

    float* Yrow = Y + (size_t)node * KPAD;
    if (tid < KPAD - 2*THALF) Yrow[2*THALF + tid] = 0.f;

    const float CPt[5] = {1.0f, 0.766044443119f, 0.173648177667f, -0.5f, -0.939692620786f};
    const float SPt[5] = {0.0f, -0.642787609687f, -0.984807753012f, -0.866025403784f, -0.342020143326f};

    #define Y_BODY(P, Q, QQ, CSIGN)                                            \
    {                                                                          \
        float cp = CPt[P], sp = SPt[P];                                        \
        float Pr = 1.f, Pi = 0.f, rp = 1.f;                                    \
        _Pragma("unroll")                                                      \
        for (int n = 0; n < 8; n++) {                                          \
            float2 Av = AL[n][QQ];                                             \
            float Ar = Av.x, Ai = (CSIGN) * Av.y;                              \
            float Xr = cp - Ar, Xi = sp - Ai;                                  \
            float m2 = Xr*Xr + Xi*Xi;                                          \
            rp *= (FSQRT(m2) + 1e-6f);                                         \
            float nPr = Pr*Xr - Pi*Xi;                                         \
            Pi = Pr*Xi + Pi*Xr; Pr = nPr;                                      \
        }                                                                      \
        float pAbs = FSQRT(Pr*Pr + Pi*Pi);                                     \
        float rp8 = FSQRT(FSQRT(FSQRT(rp)));                                   \
        float s = rp8 * FRCP(fmaxf(pAbs, 1e-20f));                             \
        int t = (P == 0) ? (Q) : (QH + ((P)-1)*M2D + (Q));                     \
        *(float2*)&Yrow[2*t] = make_float2(s*Pr, s*Pi);                        \
    }

    if (tid < QH) Y_BODY(0, tid, tid, 1.f);
    #pragma unroll
    for (int p = 1; p <= 4; p++) {
        {
            int q = tid;
            int qq = (q < QH) ? q : (M2D - q);
            float cs = (q < QH) ? 1.f : -1.f;
            Y_BODY(p, q, qq, cs);
        }
        {
            int q = tid + 256;
            if (q < M2D) {
                int qq = M2D - q;
                Y_BODY(p, q, qq, -1.f);
            }
        }
    }
    #undef Y_BODY
}

// partials[kc] = Y[:, kc-chunk] @ Gmat[kc-chunk, :] ; grid (32 Mtiles, 16 kc)
__global__ __launch_bounds__(256) void gemm_kernel(const float* __restrict__ Y,
                                                   const float* __restrict__ Gmat,
                                                   float* __restrict__ part) {
    int mtile = blockIdx.x, kc = blockIdx.y;
    int tid = threadIdx.x;
    __shared__ float Yt2[32][68];   // Yt2[k][r]
    __shared__ float Gt[32][64];
    int m0 = mtile * 64;
    int k0 = kc * KCHUNK;
    float acc[4][4] = {{0.f}};
    int tm = (tid >> 4) * 4;
    int tf = (tid & 15) * 4;
    float ra[8], rb[8];
    #pragma unroll
    for (int i = 0; i < 8; i++) {
        int l = tid + i*256;
        int r = l >> 5, kk = l & 31;
        ra[i] = Y[(size_t)(m0 + r)*KPAD + k0 + kk];
    }
    #pragma unroll
    for (int i = 0; i < 8; i++) {
        int l = tid + i*256;
        int kk = l >> 6, cc = l & 63;
        rb[i] = Gmat[(size_t)(k0 + kk)*FD + cc];
    }
    for (int ks = 0; ks < KCHUNK; ks += 32) {
        #pragma unroll
        for (int i = 0; i < 8; i++) {
            int l = tid + i*256;
            Yt2[l & 31][l >> 5] = ra[i];
        }
        #pragma unroll
        for (int i = 0; i < 8; i++) {
            int l = tid + i*256;
            Gt[l >> 6][l & 63] = rb[i];
        }
        __syncthreads();
        if (ks + 32 < KCHUNK) {
            int kn = k0 + ks + 32;
            #pragma unroll
            for (int i = 0; i < 8; i++) {
                int l = tid + i*256;
                int r = l >> 5, kk = l & 31;
                ra[i] = Y[(size_t)(m0 + r)*KPAD + kn + kk];
            }
            #pragma unroll
            for (int i = 0; i < 8; i++) {
                int l = tid + i*256;
                int kk = l >> 6, cc = l & 63;
                rb[i] = Gmat[(size_t)(kn + kk)*FD + cc];
            }
        }
        #pragma unroll 8
        for (int k = 0; k < 32; k++) {
            float4 a = *(const float4*)&Yt2[k][tm];
            float4 b = *(const float4*)&Gt[k][tf];
            acc[0][0] += a.x*b.x; acc[0][1] += a.x*b.y; acc[0][2] += a.x*b.z; acc[0][3] += a.x*b.w;
            acc[1][0] += a.y*b.x; acc[1][1] += a.y*b.y; acc[1][2] += a.y*b.z; acc[1][3] += a.y*b.w;
            acc[2][0] += a.z*b.x; acc[2][1] += a.z*b.y; acc[2][2] += a.z*b.z; acc[2][3] += a.z*b.w;
            acc[3][0] += a.w*b.x; acc[3][1] += a.w*b.y; acc[3][2] += a.w*b.z; acc[3][3] += a.w*b.w;
        }
        __syncthreads();
    }
    float* prow = part + (size_t)kc * (2048*FD);
    #pragma unroll
    for (int i = 0; i < 4; i++) {
        float4 v = make_float4(acc[i][0], acc[i][1], acc[i][2], acc[i][3]);
        *(float4*)&prow[(size_t)(m0 + tm + i)*FD + tf] = v;
    }
}

// sum 16 partials + bias + mask -> out
__global__ __launch_bounds__(256) void reduce_kernel(const float* __restrict__ part,
                                                     const float* __restrict__ bm,
                                                     const float* __restrict__ mask,
                                                     float* __restrict__ out) {
    int idx = blockIdx.x * 256 + threadIdx.x;
    if (idx >= 32768) return;
    const float4* p4 = (const float4*)part;
    float4 s = p4[idx];
    #pragma unroll
    for (int kc = 1; kc < KSPLIT; kc++) {
        float4 v = p4[(size_t)kc*32768 + idx];
        s.x += v.x; s.y += v.y; s.z += v.z; s.w += v.w;
    }
    int f0 = (idx & 15) * 4;
    int node = idx >> 4;
    float mk = mask[node];
    s.x = (s.x + bm[f0])   * mk;
    s.y = (s.y + bm[f0+1]) * mk;
    s.z = (s.z + bm[f0+2]) * mk;
    s.w = (s.w + bm[f0+3]) * mk;
    ((float4*)out)[idx] = s;
}

extern "C" void kernel_launch(void* const* d_in, const int* in_sizes, int n_in,
                              void* d_out, int out_size, void* d_ws, size_t ws_size,
                              hipStream_t stream) {
    const float* x    = (const float*)d_in[0];
    const float* adj  = (const float*)d_in[1];
    const float* mask = (const float*)d_in[2];
    const float* Wl   = (const float*)d_in[3];
    const float* bl   = (const float*)d_in[4];
    const float* Wr   = (const float*)d_in[5];
    const float* br   = (const float*)d_in[6];
    const float* Wm   = (const float*)d_in[9];
    const float* bm   = (const float*)d_in[10];
    float* out = (float*)d_out;
    float* ws  = (float*)d_ws;

    float* tw   = ws + OFF_TW;
    float* wp   = ws + OFF_WP;
    float* sumx = ws + OFF_SUMX;
    float* G1   = ws + OFF_G1;
    float* Gmat = ws + OFF_GMAT;
    float* xl   = ws + OFF_XL;
    float* xr   = ws + OFF_XR;
    float* agg  = ws + OFF_AGG;
    float* part = ws + OFF_PART;
    float* T    = ws + OFF_Y;     // alias: T dead before y_kernel writes Y
    float* Y    = ws + OFF_Y;
    float* A2   = ws + OFF_A2;
    float* Wt   = ws + OFF_WT;
    float* G1p  = ws + OFF_G1P;

    hipLaunchKernelGGL(prep_kernel, dim3(1), dim3(512), 0, stream, tw, wp, sumx);
    hipLaunchKernelGGL(build_tw_kernel, dim3((506*512 + 64*512 + 255)/256), dim3(256), 0, stream, tw, T, Wt);
    hipLaunchKernelGGL(sumx_kernel, dim3(32), dim3(64), 0, stream, x, sumx);
    hipLaunchKernelGGL(proj_kernel, dim3(2048), dim3(64), 0, stream, x, Wl, bl, Wr, br, xl, xr);
    hipLaunchKernelGGL(g1_gemm_kernel, dim3(8, 9, G1KS), dim3(256), 0, stream, T, Wm, G1p);
    hipLaunchKernelGGL(g1_reduce_kernel, dim3((G1SZ/4 + 255)/256), dim3(256), 0, stream, G1p, G1);
    hipLaunchKernelGGL(gmat_kernel, dim3(KPAD/2), dim3(64), 0, stream, G1, wp, Gmat);
    hipLaunchKernelGGL(attn_agg_kernel, dim3(2048), dim3(256), 0, stream, x, adj, xl, xr, sumx, agg);
    hipLaunchKernelGGL(a_gemm_kernel, dim3(256, 8), dim3(256), 0, stream, agg, Wt, A2);
    hipLaunchKernelGGL(y_kernel, dim3(2048), dim3(256), 0, stream, A2, Y);
    hipLaunchKernelGGL(gemm_kernel, dim3(32, KSPLIT), dim3(256), 0, stream, Y, Gmat, part);
    hipLaunchKernelGGL(reduce_kernel, dim3(128), dim3(256), 0, stream, part, bm, mask, out);
}

// Round 9
// 209.583 us; speedup vs baseline: 1.2349x; 1.0324x over previous
//
#include <hip/hip_runtime.h>
#include <math.h>

#define NN 1024
#define FD 64
#define CH 32          // K*H
#define M1D 9
#define M2D 505
#define QH 253         // q in [0,252] stored
#define THALF 2273     // half-grid points
#define KPAD 4608
#define KSPLIT 16
#define KCHUNK 288     // 4608/16 = 9*32
#define G1SZ 291456    // 9*253*64*2
#define G1KS 8         // K-split factor for g1

#define FSQRT(x) __builtin_amdgcn_sqrtf(x)
#define FRCP(x)  __builtin_amdgcn_rcpf(x)

// ws layout (floats); ws_size = 256 MiB
#define OFF_TW    0                       // 1010 (pad 1024)
#define OFF_WP    1024                    // 18 (pad 32)
#define OFF_SUMX  1056                    // 128 (pad to 1184)
#define OFF_G1    1184                    // 291456
#define OFF_GMAT  292640                  // 4608*64 = 294912
#define OFF_XL    587552                  // 65536
#define OFF_XR    653088                  // 65536
#define OFF_AGG   718624                  // 2048*512 = 1048576
#define OFF_PART  1767200                 // 16*131072 = 2097152
#define OFF_Y     3864352                 // 2048*4608 = 9437184 ; first 259072 ALIASED as T early
#define OFF_A2    13301536                // 16384*512 = 8388608
#define OFF_WT    21690144                // 64*512 = 32768
#define OFF_G1P   21722912                // 8*291456 = 2331648
// total = 24,054,560 floats = 96.2 MB

__global__ __launch_bounds__(512) void prep_kernel(float* __restrict__ tw,
                                                   float* __restrict__ wp,
                                                   float* __restrict__ sumx) {
    int t = threadIdx.x;
    if (t < M2D) {
        double a = -2.0 * M_PI * (double)t / (double)M2D;
        tw[2*t] = (float)cos(a); tw[2*t+1] = (float)sin(a);
    }
    if (t < M1D) {
        double a = -2.0 * M_PI * (double)t / (double)M1D;
        wp[2*t] = (float)cos(a); wp[2*t+1] = (float)sin(a);
    }
    if (t < 128) sumx[t] = 0.f;
}

// builds both T and Wt (merged to save a launch)
__global__ __launch_bounds__(256) void build_tw_kernel(const float* __restrict__ tw,
                                                       float* __restrict__ T,
                                                       float* __restrict__ Wt) {
    int idx = blockIdx.x * 256 + threadIdx.x;
    if (idx < 506 * 512) {
        int r = idx >> 9, m2 = idx & 511;
        float v = 0.f;
        if (m2 < M2D) {
            int q = r >> 1;
            int t = (q * m2) % M2D;
            v = (r & 1) ? -tw[2*t+1] : tw[2*t];
        }
        T[idx] = v;
    } else if (idx < 506 * 512 + 64 * 512) {
        int i2 = idx - 506 * 512;
        int m = i2 >> 9, col = i2 & 511;
        float v = 0.f;
        if (col < 506) {
            int q = col >> 1;
            int t = (q * m) % M2D;
            v = (col & 1) ? tw[2*t+1] : tw[2*t];
        }
        Wt[i2] = v;
    }
}

// 32 blocks x 64 threads: partial column sums of x
__global__ __launch_bounds__(64) void sumx_kernel(const float* __restrict__ x,
                                                  float* __restrict__ sumx) {
    int b = blockIdx.x >> 4, chunk = blockIdx.x & 15;
    int f = threadIdx.x;
    const float* xb = x + (size_t)b * NN * FD;
    float acc = 0.f;
    int j0 = chunk * 64;
    #pragma unroll 4
    for (int j = j0; j < j0 + 64; j++) acc += xb[j*FD + f];
    atomicAdd(&sumx[b*FD + f], acc);
}

// 2048 blocks x 64 threads: xl = x@Wl+bl, xr = x@Wr+br
__global__ __launch_bounds__(64) void proj_kernel(const float* __restrict__ x,
                                                  const float* __restrict__ Wl, const float* __restrict__ bl,
                                                  const float* __restrict__ Wr, const float* __restrict__ br,
                                                  float* __restrict__ xl, float* __restrict__ xr) {
    int node = blockIdx.x, tid = threadIdx.x;
    __shared__ float xrow[FD];
    xrow[tid] = x[(size_t)node*FD + tid];
    __syncthreads();
    int c = tid & 31;
    const float* W = (tid < 32) ? Wl : Wr;
    float acc = (tid < 32) ? bl[c] : br[c];
    #pragma unroll
    for (int f = 0; f < FD; f++) acc += xrow[f] * W[f*CH + c];
    float* dst = (tid < 32) ? xl : xr;
    dst[(size_t)node*CH + c] = acc;
}

// G1 partials: grid (8 mtiles, 9 m1, 8 ksplit), one-shot K=64 tile GEMM
__global__ __launch_bounds__(256) void g1_gemm_kernel(const float* __restrict__ T,
                                                      const float* __restrict__ Wm,
                                                      float* __restrict__ G1p) {
    int mt = blockIdx.x, m1 = blockIdx.y, ks = blockIdx.z;
    int tid = threadIdx.x;
    __shared__ float As[64][68];
    __shared__ float Bs[64][64];
    int r0 = mt * 64, k0 = ks * 64;
    const float* Wmb = Wm + (size_t)m1 * M2D * FD;
    float ra[16], rb[16];
    #pragma unroll
    for (int i = 0; i < 16; i++) {
        int l = tid + i*256;
        int r = l >> 6, k = l & 63;
        int rr = r0 + r;
        ra[i] = (rr < 506) ? T[(size_t)rr*512 + k0 + k] : 0.f;
    }
    #pragma unroll
    for (int i = 0; i < 16; i++) {
        int l = tid + i*256;
        int k = l >> 6, f = l & 63;
        int krow = k0 + k;
        rb[i] = (krow < M2D) ? Wmb[(size_t)krow*FD + f] : 0.f;
    }
    #pragma unroll
    for (int i = 0; i < 16; i++) {
        int l = tid + i*256;
        As[l & 63][l >> 6] = ra[i];
    }
    #pragma unroll
    for (int i = 0; i < 16; i++) {
        int l = tid + i*256;
        Bs[l >> 6][l & 63] = rb[i];
    }
    __syncthreads();
    float acc[4][4] = {{0.f}};
    int tm = (tid >> 4) * 4, tf = (tid & 15) * 4;
    #pragma unroll 8
    for (int k = 0; k < 64; k++) {
        float4 a = *(const float4*)&As[k][tm];
        float4 b = *(const float4*)&Bs[k][tf];
        acc[0][0] += a.x*b.x; acc[0][1] += a.x*b.y; acc[0][2] += a.x*b.z; acc[0][3] += a.x*b.w;
        acc[1][0] += a.y*b.x; acc[1][1] += a.y*b.y; acc[1][2] += a.y*b.z; acc[1][3] += a.y*b.w;
        acc[2][0] += a.z*b.x; acc[2][1] += a.z*b.y; acc[2][2] += a.z*b.z; acc[2][3] += a.z*b.w;
        acc[3][0] += a.w*b.x; acc[3][1] += a.w*b.y; acc[3][2] += a.w*b.z; acc[3][3] += a.w*b.w;
    }
    float* G1k = G1p + (size_t)ks * G1SZ;
    #pragma unroll
    for (int i = 0; i < 4; i++) {
        int r = r0 + tm + i;
        if (r >= 506) continue;
        int q = r >> 1, reim = r & 1;
        size_t base = (size_t)(m1*QH + q) * 128;
        #pragma unroll
        for (int j = 0; j < 4; j++)
            G1k[base + (tf + j)*2 + reim] = acc[i][j];
    }
}

// fold the 8 K-split partials
__global__ __launch_bounds__(256) void g1_reduce_kernel(const float* __restrict__ G1p,
                                                        float* __restrict__ G1) {
    int idx = blockIdx.x * 256 + threadIdx.x;
    if (idx >= G1SZ/4) return;
    const float4* p = (const float4*)G1p;
    float4 s = p[idx];
    #pragma unroll
    for (int ks = 1; ks < G1KS; ks++) {
        float4 v = p[(size_t)ks*(G1SZ/4) + idx];
        s.x += v.x; s.y += v.y; s.z += v.z; s.w += v.w;
    }
    ((float4*)G1)[idx] = s;
}

// Gmat[2t..2t+1][f] from G1: fold 9-point DFT over m1, Hermitian weight, 1/4545
__global__ __launch_bounds__(64) void gmat_kernel(const float* __restrict__ G1,
                                                  const float* __restrict__ wp,
                                                  float* __restrict__ Gmat) {
    int t = blockIdx.x;
    int f = threadIdx.x;
    if (t >= THALF) {
        Gmat[(size_t)(2*t)*FD + f] = 0.f;
        Gmat[(size_t)(2*t+1)*FD + f] = 0.f;
        return;
    }
    int p, q;
    if (t < QH) { p = 0; q = t; }
    else { int u = t - QH; p = 1 + u / M2D; q = u % M2D; }
    float gr = 0.f, gi = 0.f;
    #pragma unroll
    for (int m1 = 0; m1 < M1D; m1++) {
        float ar, ai;
        if (q < QH) { size_t o = ((size_t)(m1*QH + q)*FD + f)*2; ar = G1[o]; ai = G1[o+1]; }
        else        { size_t o = ((size_t)(m1*QH + (M2D - q))*FD + f)*2; ar = G1[o]; ai = -G1[o+1]; }
        int pm = (p * m1) % M1D;
        float cr = wp[2*pm], ci = -wp[2*pm+1];
        gr += ar*cr - ai*ci;
        gi += ar*ci + ai*cr;
    }
    float scale = (t == 0) ? (1.0f/4545.0f) : (2.0f/4545.0f);
    Gmat[(size_t)(2*t)*FD + f]   =  gr * scale;
    Gmat[(size_t)(2*t+1)*FD + f] = -gi * scale;
}

// one block (256 thr) per node. Round-8 restructure: 8-deep reg-batched Z-pass
// (was 4-unrolled serial-chain, L2-latency-exposed) + chunked qv precompute
// (2 barriers/node typical instead of 14) + 8-deep-batched gather loads.
__global__ __launch_bounds__(256) void attn_agg_kernel(const float* __restrict__ x,
                                                       const float* __restrict__ adj,
                                                       const float* __restrict__ xl,
                                                       const float* __restrict__ xr,
                                                       const float* __restrict__ sumx,
                                                       float* __restrict__ agg) {
    int node = blockIdx.x;
    int b = node >> 10;
    int tid = threadIdx.x;
    __shared__ float xr_s[CH], Zinv[CH], Sinv[CH];
    __shared__ float red[8][CH];
    __shared__ int act_list[NN + 8];
    __shared__ int act_n;
    __shared__ float qv2[64][CH];

    if (tid < CH) xr_s[tid] = xr[(size_t)node*CH + tid];
    if (tid == 0) act_n = 0;
    __syncthreads();

    int c = tid & 31, jl = tid >> 5;
    float xrc = xr_s[c];
    const float* xlb = xl + ((size_t)b << 10) * CH;
    const float* adjrow = adj + (size_t)node * NN;

    // Z-pass: 16 outer iters x 8 independent loads
    float zacc = 0.f;
    for (int j0 = jl; j0 < NN; j0 += 64) {
        float sv[8];
        #pragma unroll
        for (int u = 0; u < 8; u++) sv[u] = xlb[(j0 + u*8)*CH + c];
        #pragma unroll
        for (int u = 0; u < 8; u++) {
            float s = sv[u] + xrc;
            s = s > 0.f ? s : 0.01f * s;
            zacc += __expf(s);
        }
    }
    red[jl][c] = zacc;

    // active-list scan (4 batched loads per thread)
    float av[4];
    #pragma unroll
    for (int u = 0; u < 4; u++) av[u] = adjrow[tid + u*256];
    __syncthreads();
    if (tid < CH) {
        float z = 0.f;
        #pragma unroll
        for (int r = 0; r < 8; r++) z += red[r][tid];
        Zinv[tid] = FRCP(z);
    }
    #pragma unroll
    for (int u = 0; u < 4; u++)
        if (av[u] != 0.f) { int p = atomicAdd(&act_n, 1); act_list[p] = tid + u*256; }
    __syncthreads();
    int nact = act_n;

    int f = tid & 63, n0 = tid >> 6;
    int g = f >> 4;
    int c0 = n0*4 + g, c1 = (n0+4)*4 + g;
    const float* xb = x + ((size_t)b << 10) * FD;
    float acc0 = 0.f, acc1 = 0.f, sacc = 0.f;

    for (int base = 0; base < nact; base += 64) {
        int cnt = min(64, nact - base);
        int cntp = (cnt + 7) & ~7;
        // compute qv2 for this chunk; per-thread partial sum has fixed c=tid&31
        for (int u = tid; u < (cnt << 5); u += 256) {
            int jj = u >> 5, cc = u & 31;
            int j = act_list[base + jj];
            float s = xlb[j*CH + cc] + xr_s[cc];
            s = s > 0.f ? s : 0.01f * s;
            float pv = __expf(s) * Zinv[cc];
            float qq = fmaxf(pv, 1e-6f) - 1e-6f;
            qv2[jj][cc] = qq;
            sacc += qq;
        }
        // zero-pad qv2 rows to multiple of 8; pad act_list (last chunk only)
        for (int u = tid + (cnt << 5); u < (cntp << 5); u += 256)
            qv2[u >> 5][u & 31] = 0.f;
        if (tid < cntp - cnt) act_list[base + cnt + tid] = act_list[base];
        __syncthreads();
        // gather: 8-deep batched loads, no barriers inside
        for (int jb = 0; jb < cntp; jb += 8) {
            float xv[8];
            #pragma unroll
            for (int u = 0; u < 8; u++) xv[u] = xb[act_list[base + jb + u]*FD + f];
            #pragma unroll
            for (int u = 0; u < 8; u++) {
                acc0 += qv2[jb+u][c0] * xv[u];
                acc1 += qv2[jb+u][c1] * xv[u];
            }
        }
        __syncthreads();
    }
    red[jl][c] = sacc;
    __syncthreads();
    if (tid < CH) {
        float s = 0.f;
        #pragma unroll
        for (int r = 0; r < 8; r++) s += red[r][tid];
        Sinv[tid] = FRCP(s + (float)NN * 1e-6f);
    }
    __syncthreads();
    float sx = sumx[b*FD + f] * 1e-6f;
    agg[(size_t)node*512 + n0*FD + f]       = (acc0 + sx) * Sinv[c0];
    agg[(size_t)node*512 + (n0+4)*FD + f]   = (acc1 + sx) * Sinv[c1];
}

// A2 = agg @ Wt : [16384 x 64] @ [64 x 512]. grid (256 mtiles, 8 ntiles)
__global__ __launch_bounds__(256) void a_gemm_kernel(const float* __restrict__ agg,
                                                     const float* __restrict__ Wt,
                                                     float* __restrict__ A2) {
    int mt = blockIdx.x, nt = blockIdx.y;
    int tid = threadIdx.x;
    __shared__ float As2[64][68];
    __shared__ float Bs[64][64];
    float acc[4][4] = {{0.f}};
    int tm = (tid >> 4) * 4, tf = (tid & 15) * 4;
    float ra[16], rb[16];
    #pragma unroll
    for (int i = 0; i < 16; i++) {
        int l = tid + i*256;
        int r = l >> 6, k = l & 63;
        ra[i] = agg[(size_t)(mt*64 + r)*64 + k];
    }
    #pragma unroll
    for (int i = 0; i < 16; i++) {
        int l = tid + i*256;
        int k = l >> 6, cc = l & 63;
        rb[i] = Wt[(size_t)k*512 + nt*64 + cc];
    }
    #pragma unroll
    for (int i = 0; i < 16; i++) {
        int l = tid + i*256;
        As2[l & 63][l >> 6] = ra[i];
    }
    #pragma unroll
    for (int i = 0; i < 16; i++) {
        int l = tid + i*256;
        Bs[l >> 6][l & 63] = rb[i];
    }
    __syncthreads();
    #pragma unroll 8
    for (int k = 0; k < 64; k++) {
        float4 a = *(const float4*)&As2[k][tm];
        float4 b = *(const float4*)&Bs[k][tf];
        acc[0][0] += a.x*b.x; acc[0][1] += a.x*b.y; acc[0][2] += a.x*b.z; acc[0][3] += a.x*b.w;
        acc[1][0] += a.y*b.x; acc[1][1] += a.y*b.y; acc[1][2] += a.y*b.z; acc[1][3] += a.y*b.w;
        acc[2][0] += a.z*b.x; acc[2][1] += a.z*b.y; acc[2][2] += a.z*b.z; acc[2][3] += a.z*b.w;
        acc[3][0] += a.w*b.x; acc[3][1] += a.w*b.y; acc[3][2] += a.w*b.z; acc[3][3] += a.w*b.w;
    }
    #pragma unroll
    for (int i = 0; i < 4; i++) {
        float4 v = make_float4(acc[i][0], acc[i][1], acc[i][2], acc[i][3]);
        *(float4*)&A2[(size_t)(mt*64 + tm + i)*512 + nt*64 + tf] = v;
    }
}

// one block (256 thr) per node: Y half-grid from A2 via complex products.
__global__ __launch_bounds__(256) void y_kernel(const float* __restrict__ A2,
                                                float* __restrict__ Y) {
    int node = blockIdx.x;
    int tid = threadIdx.x;
    __shared__ float2 AL[8][QH];

    const float2* A2c = (const float2*)(A2 + (size_t)(node*8)*512);
    float2 rl[8];
    #pragma unroll
    for (int i = 0; i < 8; i++) {
        int idx = tid + i*256;
        rl[i] = (idx < 8*QH) ? A2c[(idx/QH)*256 + (idx%QH)] : make_float2(0.f, 0.f);
    }
    #pragma unroll
    for (int i = 0; i < 8; i++) {
        int idx = tid + i*256;
        if (idx < 8*QH) AL[idx/QH][idx%QH] = rl[i];
    }
    __syncthreads();

    float* Yrow = Y + (size_t)node * KPAD;
    if (tid < KPAD - 2*THALF) Yrow[2*THALF + tid] = 0.f;

    const float CPt[5] = {1.0f, 0.766044443119f, 0.173648177667f, -0.5f, -0.939692620786f};
    const float SPt[5] = {0.0f, -0.642787609687f, -0.984807753012f, -0.866025403784f, -0.342020143326f};

    #define Y_BODY(P, Q, QQ, CSIGN)                                            \
    {                                                                          \
        float cp = CPt[P], sp = SPt[P];                                        \
        float Pr = 1.f, Pi = 0.f, rp = 1.f;                                    \
        _Pragma("unroll")                                                      \
        for (int n = 0; n < 8; n++) {                                          \
            float2 Av = AL[n][QQ];                                             \
            float Ar = Av.x, Ai = (CSIGN) * Av.y;                              \
            float Xr = cp - Ar, Xi = sp - Ai;                                  \
            float m2 = Xr*Xr + Xi*Xi;                                          \
            rp *= (FSQRT(m2) + 1e-6f);                                         \
            float nPr = Pr*Xr - Pi*Xi;                                         \
            Pi = Pr*Xi + Pi*Xr; Pr = nPr;                                      \
        }                                                                      \
        float pAbs = FSQRT(Pr*Pr + Pi*Pi);                                     \
        float rp8 = FSQRT(FSQRT(FSQRT(rp)));                                   \
        float s = rp8 * FRCP(fmaxf(pAbs, 1e-20f));                             \
        int t = (P == 0) ? (Q) : (QH + ((P)-1)*M2D + (Q));                     \
        *(float2*)&Yrow[2*t] = make_float2(s*Pr, s*Pi);                        \
    }

    if (tid < QH) Y_BODY(0, tid, tid, 1.f);
    #pragma unroll
    for (int p = 1; p <= 4; p++) {
        {
            int q = tid;
            int qq = (q < QH) ? q : (M2D - q);
            float cs = (q < QH) ? 1.f : -1.f;
            Y_BODY(p, q, qq, cs);
        }
        {
            int q = tid + 256;
            if (q < M2D) {
                int qq = M2D - q;
                Y_BODY(p, q, qq, -1.f);
            }
        }
    }
    #undef Y_BODY
}

// partials[kc] = Y[:, kc-chunk] @ Gmat[kc-chunk, :] ; grid (32 Mtiles, 16 kc)
__global__ __launch_bounds__(256) void gemm_kernel(const float* __restrict__ Y,
                                                   const float* __restrict__ Gmat,
                                                   float* __restrict__ part) {
    int mtile = blockIdx.x, kc = blockIdx.y;
    int tid = threadIdx.x;
    __shared__ float Yt2[32][68];
    __shared__ float Gt[32][64];
    int m0 = mtile * 64;
    int k0 = kc * KCHUNK;
    float acc[4][4] = {{0.f}};
    int tm = (tid >> 4) * 4;
    int tf = (tid & 15) * 4;
    float ra[8], rb[8];
    #pragma unroll
    for (int i = 0; i < 8; i++) {
        int l = tid + i*256;
        int r = l >> 5, kk = l & 31;
        ra[i] = Y[(size_t)(m0 + r)*KPAD + k0 + kk];
    }
    #pragma unroll
    for (int i = 0; i < 8; i++) {
        int l = tid + i*256;
        int kk = l >> 6, cc = l & 63;
        rb[i] = Gmat[(size_t)(k0 + kk)*FD + cc];
    }
    for (int ks = 0; ks < KCHUNK; ks += 32) {
        #pragma unroll
        for (int i = 0; i < 8; i++) {
            int l = tid + i*256;
            Yt2[l & 31][l >> 5] = ra[i];
        }
        #pragma unroll
        for (int i = 0; i < 8; i++) {
            int l = tid + i*256;
            Gt[l >> 6][l & 63] = rb[i];
        }
        __syncthreads();
        if (ks + 32 < KCHUNK) {
            int kn = k0 + ks + 32;
            #pragma unroll
            for (int i = 0; i < 8; i++) {
                int l = tid + i*256;
                int r = l >> 5, kk = l & 31;
                ra[i] = Y[(size_t)(m0 + r)*KPAD + kn + kk];
            }
            #pragma unroll
            for (int i = 0; i < 8; i++) {
                int l = tid + i*256;
                int kk = l >> 6, cc = l & 63;
                rb[i] = Gmat[(size_t)(kn + kk)*FD + cc];
            }
        }
        #pragma unroll 8
        for (int k = 0; k < 32; k++) {
            float4 a = *(const float4*)&Yt2[k][tm];
            float4 b = *(const float4*)&Gt[k][tf];
            acc[0][0] += a.x*b.x; acc[0][1] += a.x*b.y; acc[0][2] += a.x*b.z; acc[0][3] += a.x*b.w;
            acc[1][0] += a.y*b.x; acc[1][1] += a.y*b.y; acc[1][2] += a.y*b.z; acc[1][3] += a.y*b.w;
            acc[2][0] += a.z*b.x; acc[2][1] += a.z*b.y; acc[2][2] += a.z*b.z; acc[2][3] += a.z*b.w;
            acc[3][0] += a.w*b.x; acc[3][1] += a.w*b.y; acc[3][2] += a.w*b.z; acc[3][3] += a.w*b.w;
        }
        __syncthreads();
    }
    float* prow = part + (size_t)kc * (2048*FD);
    #pragma unroll
    for (int i = 0; i < 4; i++) {
        float4 v = make_float4(acc[i][0], acc[i][1], acc[i][2], acc[i][3]);
        *(float4*)&prow[(size_t)(m0 + tm + i)*FD + tf] = v;
    }
}

// sum 16 partials + bias + mask -> out
__global__ __launch_bounds__(256) void reduce_kernel(const float* __restrict__ part,
                                                     const float* __restrict__ bm,
                                                     const float* __restrict__ mask,
                                                     float* __restrict__ out) {
    int idx = blockIdx.x * 256 + threadIdx.x;
    if (idx >= 32768) return;
    const float4* p4 = (const float4*)part;
    float4 s = p4[idx];
    #pragma unroll
    for (int kc = 1; kc < KSPLIT; kc++) {
        float4 v = p4[(size_t)kc*32768 + idx];
        s.x += v.x; s.y += v.y; s.z += v.z; s.w += v.w;
    }
    int f0 = (idx & 15) * 4;
    int node = idx >> 4;
    float mk = mask[node];
    s.x = (s.x + bm[f0])   * mk;
    s.y = (s.y + bm[f0+1]) * mk;
    s.z = (s.z + bm[f0+2]) * mk;
    s.w = (s.w + bm[f0+3]) * mk;
    ((float4*)out)[idx] = s;
}

extern "C" void kernel_launch(void* const* d_in, const int* in_sizes, int n_in,
                              void* d_out, int out_size, void* d_ws, size_t ws_size,
                              hipStream_t stream) {
    const float* x    = (const float*)d_in[0];
    const float* adj  = (const float*)d_in[1];
    const float* mask = (const float*)d_in[2];
    const float* Wl   = (const float*)d_in[3];
    const float* bl   = (const float*)d_in[4];
    const float* Wr   = (const float*)d_in[5];
    const float* br   = (const float*)d_in[6];
    const float* Wm   = (const float*)d_in[9];
    const float* bm   = (const float*)d_in[10];
    float* out = (float*)d_out;
    float* ws  = (float*)d_ws;

    float* tw   = ws + OFF_TW;
    float* wp   = ws + OFF_WP;
    float* sumx = ws + OFF_SUMX;
    float* G1   = ws + OFF_G1;
    float* Gmat = ws + OFF_GMAT;
    float* xl   = ws + OFF_XL;
    float* xr   = ws + OFF_XR;
    float* agg  = ws + OFF_AGG;
    float* part = ws + OFF_PART;
    float* T    = ws + OFF_Y;     // alias: T dead before y_kernel writes Y
    float* Y    = ws + OFF_Y;
    float* A2   = ws + OFF_A2;
    float* Wt   = ws + OFF_WT;
    float* G1p  = ws + OFF_G1P;

    hipLaunchKernelGGL(prep_kernel, dim3(1), dim3(512), 0, stream, tw, wp, sumx);
    hipLaunchKernelGGL(build_tw_kernel, dim3((506*512 + 64*512 + 255)/256), dim3(256), 0, stream, tw, T, Wt);
    hipLaunchKernelGGL(sumx_kernel, dim3(32), dim3(64), 0, stream, x, sumx);
    hipLaunchKernelGGL(proj_kernel, dim3(2048), dim3(64), 0, stream, x, Wl, bl, Wr, br, xl, xr);
    hipLaunchKernelGGL(g1_gemm_kernel, dim3(8, 9, G1KS), dim3(256), 0, stream, T, Wm, G1p);
    hipLaunchKernelGGL(g1_reduce_kernel, dim3((G1SZ/4 + 255)/256), dim3(256), 0, stream, G1p, G1);
    hipLaunchKernelGGL(gmat_kernel, dim3(KPAD/2), dim3(64), 0, stream, G1, wp, Gmat);
    hipLaunchKernelGGL(attn_agg_kernel, dim3(2048), dim3(256), 0, stream, x, adj, xl, xr, sumx, agg);
    hipLaunchKernelGGL(a_gemm_kernel, dim3(256, 8), dim3(256), 0, stream, agg, Wt, A2);
    hipLaunchKernelGGL(y_kernel, dim3(2048), dim3(256), 0, stream, A2, Y);
    hipLaunchKernelGGL(gemm_kernel, dim3(32, KSPLIT), dim3(256), 0, stream, Y, Gmat, part);
    hipLaunchKernelGGL(reduce_kernel, dim3(128), dim3(256), 0, stream, part, bm, mask, out);
}

// Round 10
// 203.352 us; speedup vs baseline: 1.2728x; 1.0306x over previous
//
#include <hip/hip_runtime.h>
#include <math.h>

#define NN 1024
#define FD 64
#define CH 32          // K*H
#define M1D 9
#define M2D 505
#define QH 253         // q in [0,252] stored
#define THALF 2273     // half-grid points
#define KPAD 4608
#define KSPLIT 24
#define KCHUNK 192     // 4608/24 = 6*32
#define G1SZ 291456    // 9*253*64*2
#define G1KS 8         // K-split factor for g1

#define FSQRT(x) __builtin_amdgcn_sqrtf(x)
#define FRCP(x)  __builtin_amdgcn_rcpf(x)

// ws layout (floats); ws_size = 256 MiB
#define OFF_TW    0                       // 1010 (pad 1024)
#define OFF_WP    1024                    // 18 (pad 32)
#define OFF_SUMX  1056                    // 128 (pad to 1184)
#define OFF_G1    1184                    // 291456
#define OFF_GMAT  292640                  // 4608*64 = 294912
#define OFF_XL    587552                  // 65536
#define OFF_XR    653088                  // 65536
#define OFF_AGG   718624                  // 2048*512 = 1048576
#define OFF_PART  1767200                 // 24*131072 = 3145728
#define OFF_Y     4912928                 // 2048*4608 = 9437184 ; first 259072 ALIASED as T early
#define OFF_A2    14350112                // 16384*512 = 8388608
#define OFF_WT    22738720                // 64*512 = 32768
#define OFF_G1P   22771488                // 8*291456 = 2331648
// total = 25,103,136 floats = 100.4 MB

__global__ __launch_bounds__(512) void prep_kernel(float* __restrict__ tw,
                                                   float* __restrict__ wp,
                                                   float* __restrict__ sumx) {
    int t = threadIdx.x;
    if (t < M2D) {
        double a = -2.0 * M_PI * (double)t / (double)M2D;
        tw[2*t] = (float)cos(a); tw[2*t+1] = (float)sin(a);
    }
    if (t < M1D) {
        double a = -2.0 * M_PI * (double)t / (double)M1D;
        wp[2*t] = (float)cos(a); wp[2*t+1] = (float)sin(a);
    }
    if (t < 128) sumx[t] = 0.f;
}

// builds both T and Wt (merged to save a launch)
__global__ __launch_bounds__(256) void build_tw_kernel(const float* __restrict__ tw,
                                                       float* __restrict__ T,
                                                       float* __restrict__ Wt) {
    int idx = blockIdx.x * 256 + threadIdx.x;
    if (idx < 506 * 512) {
        int r = idx >> 9, m2 = idx & 511;
        float v = 0.f;
        if (m2 < M2D) {
            int q = r >> 1;
            int t = (q * m2) % M2D;
            v = (r & 1) ? -tw[2*t+1] : tw[2*t];
        }
        T[idx] = v;
    } else if (idx < 506 * 512 + 64 * 512) {
        int i2 = idx - 506 * 512;
        int m = i2 >> 9, col = i2 & 511;
        float v = 0.f;
        if (col < 506) {
            int q = col >> 1;
            int t = (q * m) % M2D;
            v = (col & 1) ? tw[2*t+1] : tw[2*t];
        }
        Wt[i2] = v;
    }
}

// 32 blocks x 64 threads: partial column sums of x
__global__ __launch_bounds__(64) void sumx_kernel(const float* __restrict__ x,
                                                  float* __restrict__ sumx) {
    int b = blockIdx.x >> 4, chunk = blockIdx.x & 15;
    int f = threadIdx.x;
    const float* xb = x + (size_t)b * NN * FD;
    float acc = 0.f;
    int j0 = chunk * 64;
    #pragma unroll 4
    for (int j = j0; j < j0 + 64; j++) acc += xb[j*FD + f];
    atomicAdd(&sumx[b*FD + f], acc);
}

// 2048 blocks x 64 threads: xl = x@Wl+bl, xr = x@Wr+br
__global__ __launch_bounds__(64) void proj_kernel(const float* __restrict__ x,
                                                  const float* __restrict__ Wl, const float* __restrict__ bl,
                                                  const float* __restrict__ Wr, const float* __restrict__ br,
                                                  float* __restrict__ xl, float* __restrict__ xr) {
    int node = blockIdx.x, tid = threadIdx.x;
    __shared__ float xrow[FD];
    xrow[tid] = x[(size_t)node*FD + tid];
    __syncthreads();
    int c = tid & 31;
    const float* W = (tid < 32) ? Wl : Wr;
    float acc = (tid < 32) ? bl[c] : br[c];
    #pragma unroll
    for (int f = 0; f < FD; f++) acc += xrow[f] * W[f*CH + c];
    float* dst = (tid < 32) ? xl : xr;
    dst[(size_t)node*CH + c] = acc;
}

// G1 partials: grid (8 mtiles, 9 m1, 8 ksplit), one-shot K=64 tile GEMM
__global__ __launch_bounds__(256) void g1_gemm_kernel(const float* __restrict__ T,
                                                      const float* __restrict__ Wm,
                                                      float* __restrict__ G1p) {
    int mt = blockIdx.x, m1 = blockIdx.y, ks = blockIdx.z;
    int tid = threadIdx.x;
    __shared__ float As[64][68];
    __shared__ float Bs[64][64];
    int r0 = mt * 64, k0 = ks * 64;
    const float* Wmb = Wm + (size_t)m1 * M2D * FD;
    float ra[16], rb[16];
    #pragma unroll
    for (int i = 0; i < 16; i++) {
        int l = tid + i*256;
        int r = l >> 6, k = l & 63;
        int rr = r0 + r;
        ra[i] = (rr < 506) ? T[(size_t)rr*512 + k0 + k] : 0.f;
    }
    #pragma unroll
    for (int i = 0; i < 16; i++) {
        int l = tid + i*256;
        int k = l >> 6, f = l & 63;
        int krow = k0 + k;
        rb[i] = (krow < M2D) ? Wmb[(size_t)krow*FD + f] : 0.f;
    }
    #pragma unroll
    for (int i = 0; i < 16; i++) {
        int l = tid + i*256;
        As[l & 63][l >> 6] = ra[i];
    }
    #pragma unroll
    for (int i = 0; i < 16; i++) {
        int l = tid + i*256;
        Bs[l >> 6][l & 63] = rb[i];
    }
    __syncthreads();
    float acc[4][4] = {{0.f}};
    int tm = (tid >> 4) * 4, tf = (tid & 15) * 4;
    #pragma unroll 8
    for (int k = 0; k < 64; k++) {
        float4 a = *(const float4*)&As[k][tm];
        float4 b = *(const float4*)&Bs[k][tf];
        acc[0][0] += a.x*b.x; acc[0][1] += a.x*b.y; acc[0][2] += a.x*b.z; acc[0][3] += a.x*b.w;
        acc[1][0] += a.y*b.x; acc[1][1] += a.y*b.y; acc[1][2] += a.y*b.z; acc[1][3] += a.y*b.w;
        acc[2][0] += a.z*b.x; acc[2][1] += a.z*b.y; acc[2][2] += a.z*b.z; acc[2][3] += a.z*b.w;
        acc[3][0] += a.w*b.x; acc[3][1] += a.w*b.y; acc[3][2] += a.w*b.z; acc[3][3] += a.w*b.w;
    }
    float* G1k = G1p + (size_t)ks * G1SZ;
    #pragma unroll
    for (int i = 0; i < 4; i++) {
        int r = r0 + tm + i;
        if (r >= 506) continue;
        int q = r >> 1, reim = r & 1;
        size_t base = (size_t)(m1*QH + q) * 128;
        #pragma unroll
        for (int j = 0; j < 4; j++)
            G1k[base + (tf + j)*2 + reim] = acc[i][j];
    }
}

// fold the 8 K-split partials
__global__ __launch_bounds__(256) void g1_reduce_kernel(const float* __restrict__ G1p,
                                                        float* __restrict__ G1) {
    int idx = blockIdx.x * 256 + threadIdx.x;
    if (idx >= G1SZ/4) return;
    const float4* p = (const float4*)G1p;
    float4 s = p[idx];
    #pragma unroll
    for (int ks = 1; ks < G1KS; ks++) {
        float4 v = p[(size_t)ks*(G1SZ/4) + idx];
        s.x += v.x; s.y += v.y; s.z += v.z; s.w += v.w;
    }
    ((float4*)G1)[idx] = s;
}

// Gmat[2t..2t+1][f] from G1: fold 9-point DFT over m1, Hermitian weight, 1/4545
__global__ __launch_bounds__(64) void gmat_kernel(const float* __restrict__ G1,
                                                  const float* __restrict__ wp,
                                                  float* __restrict__ Gmat) {
    int t = blockIdx.x;
    int f = threadIdx.x;
    if (t >= THALF) {
        Gmat[(size_t)(2*t)*FD + f] = 0.f;
        Gmat[(size_t)(2*t+1)*FD + f] = 0.f;
        return;
    }
    int p, q;
    if (t < QH) { p = 0; q = t; }
    else { int u = t - QH; p = 1 + u / M2D; q = u % M2D; }
    float gr = 0.f, gi = 0.f;
    #pragma unroll
    for (int m1 = 0; m1 < M1D; m1++) {
        float ar, ai;
        if (q < QH) { size_t o = ((size_t)(m1*QH + q)*FD + f)*2; ar = G1[o]; ai = G1[o+1]; }
        else        { size_t o = ((size_t)(m1*QH + (M2D - q))*FD + f)*2; ar = G1[o]; ai = -G1[o+1]; }
        int pm = (p * m1) % M1D;
        float cr = wp[2*pm], ci = -wp[2*pm+1];
        gr += ar*cr - ai*ci;
        gi += ar*ci + ai*cr;
    }
    float scale = (t == 0) ? (1.0f/4545.0f) : (2.0f/4545.0f);
    Gmat[(size_t)(2*t)*FD + f]   =  gr * scale;
    Gmat[(size_t)(2*t+1)*FD + f] = -gi * scale;
}

// one block (256 thr) per node. Round-9: float2 Z-pass (halves load-issue count).
__global__ __launch_bounds__(256) void attn_agg_kernel(const float* __restrict__ x,
                                                       const float* __restrict__ adj,
                                                       const float* __restrict__ xl,
                                                       const float* __restrict__ xr,
                                                       const float* __restrict__ sumx,
                                                       float* __restrict__ agg) {
    int node = blockIdx.x;
    int b = node >> 10;
    int tid = threadIdx.x;
    __shared__ float xr_s[CH], Zinv[CH], Sinv[CH];
    __shared__ float red16[16][CH];
    __shared__ int act_list[NN + 8];
    __shared__ int act_n;
    __shared__ float qv2[64][CH];

    if (tid < CH) xr_s[tid] = xr[(size_t)node*CH + tid];
    if (tid == 0) act_n = 0;
    __syncthreads();

    int c = tid & 31, jl = tid >> 5;
    const float* xlb = xl + ((size_t)b << 10) * CH;
    const float* adjrow = adj + (size_t)node * NN;

    // Z-pass: float2 per thread (c-pair), 8 outer x 8 independent loads
    int c2 = tid & 15, jl16 = tid >> 4;
    const float2* xlb2 = (const float2*)xlb;
    float xrcx = xr_s[2*c2], xrcy = xr_s[2*c2+1];
    float zx = 0.f, zy = 0.f;
    for (int j0 = jl16; j0 < NN; j0 += 128) {
        float2 sv[8];
        #pragma unroll
        for (int u = 0; u < 8; u++) sv[u] = xlb2[(size_t)(j0 + u*16)*16 + c2];
        #pragma unroll
        for (int u = 0; u < 8; u++) {
            float s0 = sv[u].x + xrcx; s0 = s0 > 0.f ? s0 : 0.01f * s0;
            float s1 = sv[u].y + xrcy; s1 = s1 > 0.f ? s1 : 0.01f * s1;
            zx += __expf(s0); zy += __expf(s1);
        }
    }
    red16[jl16][2*c2]   = zx;
    red16[jl16][2*c2+1] = zy;

    // active-list scan (4 batched loads per thread)
    float av[4];
    #pragma unroll
    for (int u = 0; u < 4; u++) av[u] = adjrow[tid + u*256];
    __syncthreads();
    if (tid < CH) {
        float z = 0.f;
        #pragma unroll
        for (int r = 0; r < 16; r++) z += red16[r][tid];
        Zinv[tid] = FRCP(z);
    }
    #pragma unroll
    for (int u = 0; u < 4; u++)
        if (av[u] != 0.f) { int p = atomicAdd(&act_n, 1); act_list[p] = tid + u*256; }
    __syncthreads();
    int nact = act_n;

    int f = tid & 63, n0 = tid >> 6;
    int g = f >> 4;
    int c0 = n0*4 + g, c1 = (n0+4)*4 + g;
    const float* xb = x + ((size_t)b << 10) * FD;
    float acc0 = 0.f, acc1 = 0.f, sacc = 0.f;

    for (int base = 0; base < nact; base += 64) {
        int cnt = min(64, nact - base);
        int cntp = (cnt + 7) & ~7;
        for (int u = tid; u < (cnt << 5); u += 256) {
            int jj = u >> 5, cc = u & 31;
            int j = act_list[base + jj];
            float s = xlb[j*CH + cc] + xr_s[cc];
            s = s > 0.f ? s : 0.01f * s;
            float pv = __expf(s) * Zinv[cc];
            float qq = fmaxf(pv, 1e-6f) - 1e-6f;
            qv2[jj][cc] = qq;
            sacc += qq;
        }
        for (int u = tid + (cnt << 5); u < (cntp << 5); u += 256)
            qv2[u >> 5][u & 31] = 0.f;
        if (tid < cntp - cnt) act_list[base + cnt + tid] = act_list[base];
        __syncthreads();
        for (int jb = 0; jb < cntp; jb += 8) {
            float xv[8];
            #pragma unroll
            for (int u = 0; u < 8; u++) xv[u] = xb[act_list[base + jb + u]*FD + f];
            #pragma unroll
            for (int u = 0; u < 8; u++) {
                acc0 += qv2[jb+u][c0] * xv[u];
                acc1 += qv2[jb+u][c1] * xv[u];
            }
        }
        __syncthreads();
    }
    red16[jl][c] = sacc;
    __syncthreads();
    if (tid < CH) {
        float s = 0.f;
        #pragma unroll
        for (int r = 0; r < 8; r++) s += red16[r][tid];
        Sinv[tid] = FRCP(s + (float)NN * 1e-6f);
    }
    __syncthreads();
    float sx = sumx[b*FD + f] * 1e-6f;
    agg[(size_t)node*512 + n0*FD + f]       = (acc0 + sx) * Sinv[c0];
    agg[(size_t)node*512 + (n0+4)*FD + f]   = (acc1 + sx) * Sinv[c1];
}

// A2 = agg @ Wt : [16384 x 64] @ [64 x 512]. grid (256 mtiles, 8 ntiles)
__global__ __launch_bounds__(256) void a_gemm_kernel(const float* __restrict__ agg,
                                                     const float* __restrict__ Wt,
                                                     float* __restrict__ A2) {
    int mt = blockIdx.x, nt = blockIdx.y;
    int tid = threadIdx.x;
    __shared__ float As2[64][68];
    __shared__ float Bs[64][64];
    float acc[4][4] = {{0.f}};
    int tm = (tid >> 4) * 4, tf = (tid & 15) * 4;
    float ra[16], rb[16];
    #pragma unroll
    for (int i = 0; i < 16; i++) {
        int l = tid + i*256;
        int r = l >> 6, k = l & 63;
        ra[i] = agg[(size_t)(mt*64 + r)*64 + k];
    }
    #pragma unroll
    for (int i = 0; i < 16; i++) {
        int l = tid + i*256;
        int k = l >> 6, cc = l & 63;
        rb[i] = Wt[(size_t)k*512 + nt*64 + cc];
    }
    #pragma unroll
    for (int i = 0; i < 16; i++) {
        int l = tid + i*256;
        As2[l & 63][l >> 6] = ra[i];
    }
    #pragma unroll
    for (int i = 0; i < 16; i++) {
        int l = tid + i*256;
        Bs[l >> 6][l & 63] = rb[i];
    }
    __syncthreads();
    #pragma unroll 8
    for (int k = 0; k < 64; k++) {
        float4 a = *(const float4*)&As2[k][tm];
        float4 b = *(const float4*)&Bs[k][tf];
        acc[0][0] += a.x*b.x; acc[0][1] += a.x*b.y; acc[0][2] += a.x*b.z; acc[0][3] += a.x*b.w;
        acc[1][0] += a.y*b.x; acc[1][1] += a.y*b.y; acc[1][2] += a.y*b.z; acc[1][3] += a.y*b.w;
        acc[2][0] += a.z*b.x; acc[2][1] += a.z*b.y; acc[2][2] += a.z*b.z; acc[2][3] += a.z*b.w;
        acc[3][0] += a.w*b.x; acc[3][1] += a.w*b.y; acc[3][2] += a.w*b.z; acc[3][3] += a.w*b.w;
    }
    #pragma unroll
    for (int i = 0; i < 4; i++) {
        float4 v = make_float4(acc[i][0], acc[i][1], acc[i][2], acc[i][3]);
        *(float4*)&A2[(size_t)(mt*64 + tm + i)*512 + nt*64 + tf] = v;
    }
}

// one block (256 thr) per node: Y half-grid from A2.
// Round-9: rp = Π(m2) then ^(1/16) — drops 8 per-factor sqrts (the +1e-6 inside
// the geo-mean is ~1e-6 relative here; out-contribution « threshold).
__global__ __launch_bounds__(256) void y_kernel(const float* __restrict__ A2,
                                                float* __restrict__ Y) {
    int node = blockIdx.x;
    int tid = threadIdx.x;
    __shared__ float2 AL[8][QH];

    const float2* A2c = (const float2*)(A2 + (size_t)(node*8)*512);
    float2 rl[8];
    #pragma unroll
    for (int i = 0; i < 8; i++) {
        int idx = tid + i*256;
        rl[i] = (idx < 8*QH) ? A2c[(idx/QH)*256 + (idx%QH)] : make_float2(0.f, 0.f);
    }
    #pragma unroll
    for (int i = 0; i < 8; i++) {
        int idx = tid + i*256;
        if (idx < 8*QH) AL[idx/QH][idx%QH] = rl[i];
    }
    __syncthreads();

    float* Yrow = Y + (size_t)node * KPAD;
    if (tid < KPAD - 2*THALF) Yrow[2*THALF + tid] = 0.f;

    const float CPt[5] = {1.0f, 0.766044443119f, 0.173648177667f, -0.5f, -0.939692620786f};
    const float SPt[5] = {0.0f, -0.642787609687f, -0.984807753012f, -0.866025403784f, -0.342020143326f};

    #define Y_BODY(P, Q, QQ, CSIGN)                                            \
    {                                                                          \
        float cp = CPt[P], sp = SPt[P];                                        \
        float Pr = 1.f, Pi = 0.f, rp2 = 1.f;                                   \
        _Pragma("unroll")                                                      \
        for (int n = 0; n < 8; n++) {                                          \
            float2 Av = AL[n][QQ];                                             \
            float Ar = Av.x, Ai = (CSIGN) * Av.y;                              \
            float Xr = cp - Ar, Xi = sp - Ai;                                  \
            rp2 *= (Xr*Xr + Xi*Xi);                                            \
            float nPr = Pr*Xr - Pi*Xi;                                         \
            Pi = Pr*Xi + Pi*Xr; Pr = nPr;                                      \
        }                                                                      \
        float pAbs = FSQRT(Pr*Pr + Pi*Pi);                                     \
        float rp8 = FSQRT(FSQRT(FSQRT(FSQRT(rp2))));                           \
        float s = rp8 * FRCP(fmaxf(pAbs, 1e-20f));                             \
        int t = (P == 0) ? (Q) : (QH + ((P)-1)*M2D + (Q));                     \
        *(float2*)&Yrow[2*t] = make_float2(s*Pr, s*Pi);                        \
    }

    if (tid < QH) Y_BODY(0, tid, tid, 1.f);
    #pragma unroll
    for (int p = 1; p <= 4; p++) {
        {
            int q = tid;
            int qq = (q < QH) ? q : (M2D - q);
            float cs = (q < QH) ? 1.f : -1.f;
            Y_BODY(p, q, qq, cs);
        }
        {
            int q = tid + 256;
            if (q < M2D) {
                int qq = M2D - q;
                Y_BODY(p, q, qq, -1.f);
            }
        }
    }
    #undef Y_BODY
}

// partials[kc] = Y[:, kc-chunk] @ Gmat[kc-chunk, :] ; grid (32 Mtiles, 24 kc)
__global__ __launch_bounds__(256) void gemm_kernel(const float* __restrict__ Y,
                                                   const float* __restrict__ Gmat,
                                                   float* __restrict__ part) {
    int mtile = blockIdx.x, kc = blockIdx.y;
    int tid = threadIdx.x;
    __shared__ float Yt2[32][68];
    __shared__ float Gt[32][64];
    int m0 = mtile * 64;
    int k0 = kc * KCHUNK;
    float acc[4][4] = {{0.f}};
    int tm = (tid >> 4) * 4;
    int tf = (tid & 15) * 4;
    float ra[8], rb[8];
    #pragma unroll
    for (int i = 0; i < 8; i++) {
        int l = tid + i*256;
        int r = l >> 5, kk = l & 31;
        ra[i] = Y[(size_t)(m0 + r)*KPAD + k0 + kk];
    }
    #pragma unroll
    for (int i = 0; i < 8; i++) {
        int l = tid + i*256;
        int kk = l >> 6, cc = l & 63;
        rb[i] = Gmat[(size_t)(k0 + kk)*FD + cc];
    }
    for (int ks = 0; ks < KCHUNK; ks += 32) {
        #pragma unroll
        for (int i = 0; i < 8; i++) {
            int l = tid + i*256;
            Yt2[l & 31][l >> 5] = ra[i];
        }
        #pragma unroll
        for (int i = 0; i < 8; i++) {
            int l = tid + i*256;
            Gt[l >> 6][l & 63] = rb[i];
        }
        __syncthreads();
        if (ks + 32 < KCHUNK) {
            int kn = k0 + ks + 32;
            #pragma unroll
            for (int i = 0; i < 8; i++) {
                int l = tid + i*256;
                int r = l >> 5, kk = l & 31;
                ra[i] = Y[(size_t)(m0 + r)*KPAD + kn + kk];
            }
            #pragma unroll
            for (int i = 0; i < 8; i++) {
                int l = tid + i*256;
                int kk = l >> 6, cc = l & 63;
                rb[i] = Gmat[(size_t)(kn + kk)*FD + cc];
            }
        }
        #pragma unroll 8
        for (int k = 0; k < 32; k++) {
            float4 a = *(const float4*)&Yt2[k][tm];
            float4 b = *(const float4*)&Gt[k][tf];
            acc[0][0] += a.x*b.x; acc[0][1] += a.x*b.y; acc[0][2] += a.x*b.z; acc[0][3] += a.x*b.w;
            acc[1][0] += a.y*b.x; acc[1][1] += a.y*b.y; acc[1][2] += a.y*b.z; acc[1][3] += a.y*b.w;
            acc[2][0] += a.z*b.x; acc[2][1] += a.z*b.y; acc[2][2] += a.z*b.z; acc[2][3] += a.z*b.w;
            acc[3][0] += a.w*b.x; acc[3][1] += a.w*b.y; acc[3][2] += a.w*b.z; acc[3][3] += a.w*b.w;
        }
        __syncthreads();
    }
    float* prow = part + (size_t)kc * (2048*FD);
    #pragma unroll
    for (int i = 0; i < 4; i++) {
        float4 v = make_float4(acc[i][0], acc[i][1], acc[i][2], acc[i][3]);
        *(float4*)&prow[(size_t)(m0 + tm + i)*FD + tf] = v;
    }
}

// sum 24 partials + bias + mask -> out
__global__ __launch_bounds__(256) void reduce_kernel(const float* __restrict__ part,
                                                     const float* __restrict__ bm,
                                                     const float* __restrict__ mask,
                                                     float* __restrict__ out) {
    int idx = blockIdx.x * 256 + threadIdx.x;
    if (idx >= 32768) return;
    const float4* p4 = (const float4*)part;
    float4 s = p4[idx];
    #pragma unroll
    for (int kc = 1; kc < KSPLIT; kc++) {
        float4 v = p4[(size_t)kc*32768 + idx];
        s.x += v.x; s.y += v.y; s.z += v.z; s.w += v.w;
    }
    int f0 = (idx & 15) * 4;
    int node = idx >> 4;
    float mk = mask[node];
    s.x = (s.x + bm[f0])   * mk;
    s.y = (s.y + bm[f0+1]) * mk;
    s.z = (s.z + bm[f0+2]) * mk;
    s.w = (s.w + bm[f0+3]) * mk;
    ((float4*)out)[idx] = s;
}

extern "C" void kernel_launch(void* const* d_in, const int* in_sizes, int n_in,
                              void* d_out, int out_size, void* d_ws, size_t ws_size,
                              hipStream_t stream) {
    const float* x    = (const float*)d_in[0];
    const float* adj  = (const float*)d_in[1];
    const float* mask = (const float*)d_in[2];
    const float* Wl   = (const float*)d_in[3];
    const float* bl   = (const float*)d_in[4];
    const float* Wr   = (const float*)d_in[5];
    const float* br   = (const float*)d_in[6];
    const float* Wm   = (const float*)d_in[9];
    const float* bm   = (const float*)d_in[10];
    float* out = (float*)d_out;
    float* ws  = (float*)d_ws;

    float* tw   = ws + OFF_TW;
    float* wp   = ws + OFF_WP;
    float* sumx = ws + OFF_SUMX;
    float* G1   = ws + OFF_G1;
    float* Gmat = ws + OFF_GMAT;
    float* xl   = ws + OFF_XL;
    float* xr   = ws + OFF_XR;
    float* agg  = ws + OFF_AGG;
    float* part = ws + OFF_PART;
    float* T    = ws + OFF_Y;     // alias: T dead before y_kernel writes Y
    float* Y    = ws + OFF_Y;
    float* A2   = ws + OFF_A2;
    float* Wt   = ws + OFF_WT;
    float* G1p  = ws + OFF_G1P;

    hipLaunchKernelGGL(prep_kernel, dim3(1), dim3(512), 0, stream, tw, wp, sumx);
    hipLaunchKernelGGL(build_tw_kernel, dim3((506*512 + 64*512 + 255)/256), dim3(256), 0, stream, tw, T, Wt);
    hipLaunchKernelGGL(sumx_kernel, dim3(32), dim3(64), 0, stream, x, sumx);
    hipLaunchKernelGGL(proj_kernel, dim3(2048), dim3(64), 0, stream, x, Wl, bl, Wr, br, xl, xr);
    hipLaunchKernelGGL(g1_gemm_kernel, dim3(8, 9, G1KS), dim3(256), 0, stream, T, Wm, G1p);
    hipLaunchKernelGGL(g1_reduce_kernel, dim3((G1SZ/4 + 255)/256), dim3(256), 0, stream, G1p, G1);
    hipLaunchKernelGGL(gmat_kernel, dim3(KPAD/2), dim3(64), 0, stream, G1, wp, Gmat);
    hipLaunchKernelGGL(attn_agg_kernel, dim3(2048), dim3(256), 0, stream, x, adj, xl, xr, sumx, agg);
    hipLaunchKernelGGL(a_gemm_kernel, dim3(256, 8), dim3(256), 0, stream, agg, Wt, A2);
    hipLaunchKernelGGL(y_kernel, dim3(2048), dim3(256), 0, stream, A2, Y);
    hipLaunchKernelGGL(gemm_kernel, dim3(32, KSPLIT), dim3(256), 0, stream, Y, Gmat, part);
    hipLaunchKernelGGL(reduce_kernel, dim3(128), dim3(256), 0, stream, part, bm, mask, out);
}